// Round 8
// baseline (9152.303 us; speedup 1.0000x reference)
//
#include <hip/hip_runtime.h>
#include <math.h>

// ---------------------------------------------------------------------------
// DiT-RWKV forward. bf16-MFMA everywhere + chunked MFMA WKV.
// Round 8: wd-decay GEMM fused into wkv (MFMA in-block), tm_w2 bf16,
// td1 folded into grouped rkvg launch (with c<N guard). 10 dispatches/layer.
// B=32, T=256, C=768, H=12, N=64, FF=2688, L=12, HC=384, IMG=32, P=2
// ---------------------------------------------------------------------------

typedef short  s16x8 __attribute__((ext_vector_type(8)));
typedef float  f32x4 __attribute__((ext_vector_type(4)));
typedef __attribute__((address_space(1))) const void as1_cv;
typedef __attribute__((address_space(3))) void as3_v;

#define GLDS16(gp, lp) __builtin_amdgcn_global_load_lds( \
    (as1_cv*)(unsigned long long)(const void*)(gp), \
    (as3_v*)(unsigned int)(unsigned long long)(void*)(lp), 16, 0, 0)

static __device__ __forceinline__ float sigf(float x){ return 1.f/(1.f+expf(-x)); }
static __device__ __forceinline__ unsigned short f2b(float x){
  unsigned int u = __builtin_bit_cast(unsigned int, x);
  unsigned int r = (u + 0x7FFFu + ((u >> 16) & 1u)) >> 16;
  return (unsigned short)r;
}
static __device__ __forceinline__ float b2f(unsigned short h){
  unsigned int u = ((unsigned int)h)<<16; return __builtin_bit_cast(float,u);
}

// ---------------- workspace layout (float offsets) ----------------
static const size_t O_XS    = 0ull;
static const size_t O_HMOD  = 6291456ull;    // hmod16 (bf16)
static const size_t O_ADA   = 12582912ull;
static const size_t O_FLA   = 14352384ull;
static const size_t O_T2    = 14401536ull;
static const size_t O_SC    = 14426112ull;
static const size_t O_TI    = 14450688ull;
static const size_t O_T1    = 14458880ull;
static const size_t O_ST1   = 14483456ull;
static const size_t O_ST2   = 14485504ull;
static const size_t O_XEW16 = 14487552ull;
static const size_t O_WL16  = 15077376ull;   // 4067328 f (8134656 bf16)
static const size_t O_BIG   = 19144704ull;
// layer-phase members (offsets within BIG):
static const size_t L_XW    = 0ull;
static const size_t L_XX    = 6291456ull;    // xx16
static const size_t L_XXX   = 12582912ull;   // xxx16 then rb16
static const size_t L_KB    = 18874368ull;
static const size_t L_VB    = 25165824ull;
static const size_t L_GB    = 31457280ull;   // gb16
static const size_t L_WD    = 37748736ull;   // (free now)
static const size_t L_MIXB  = 50331648ull;
static const size_t L_WT    = 51642368ull;   // wt16: 8192 x 64 bf16
static const size_t L_XK16  = 52166656ull;
static const size_t L_XV16  = 55312384ull;
static const size_t L_XR16  = 58458112ull;
static const size_t L_XG16  = 61603840ull;
static const size_t L_GNH16 = 64749568ull;
static const size_t L_KBIG16= 67895296ull;
// stem-phase members (alias onto BIG):
static const size_t S_IMG1  = 0ull;
static const size_t S_IMG2  = 12582912ull;
static const size_t S_PAD16 = 25165824ull;
static const size_t S_WTAP16= 33128448ull;
static const size_t S_PM16  = 34971648ull;

// ---------------- fp32 GEMM (small/odd shapes) ----------------
enum { EPI_NONE=0, EPI_SILU=1 };

template<int EPI, bool TB>
__global__ __launch_bounds__(256) void gemm_k(
    const float* __restrict__ A, const float* __restrict__ B,
    float* __restrict__ C, const float* __restrict__ bias,
    int M, int N, int K)
{
  __shared__ __align__(16) float As[16][68];
  __shared__ __align__(16) float Bs[16][68];
  const int tid = threadIdx.x;
  const int tx = tid & 15, ty = tid >> 4;
  const int row0 = blockIdx.y * 64, col0 = blockIdx.x * 64;
  const int lr = tid >> 2;
  const int lk = (tid & 3) << 2;
  float acc[4][4] = {};
  for (int k0 = 0; k0 < K; k0 += 16) {
    {
      int gr = row0 + lr;
      float4 v = make_float4(0.f,0.f,0.f,0.f);
      if (gr < M) v = *reinterpret_cast<const float4*>(A + (size_t)gr*K + (k0 + lk));
      As[lk+0][lr]=v.x; As[lk+1][lr]=v.y; As[lk+2][lr]=v.z; As[lk+3][lr]=v.w;
    }
    if (TB) {
      int gr = col0 + lr;
      float4 v = make_float4(0.f,0.f,0.f,0.f);
      if (gr < N) v = *reinterpret_cast<const float4*>(B + (size_t)gr*K + (k0 + lk));
      Bs[lk+0][lr]=v.x; Bs[lk+1][lr]=v.y; Bs[lk+2][lr]=v.z; Bs[lk+3][lr]=v.w;
    } else {
      int kr = tid >> 4;
      int gc = col0 + ((tid & 15) << 2);
      float4 v = make_float4(0.f,0.f,0.f,0.f);
      if (gc < N) v = *reinterpret_cast<const float4*>(B + (size_t)(k0+kr)*N + gc);
      Bs[kr][((tid&15)<<2)+0]=v.x; Bs[kr][((tid&15)<<2)+1]=v.y;
      Bs[kr][((tid&15)<<2)+2]=v.z; Bs[kr][((tid&15)<<2)+3]=v.w;
    }
    __syncthreads();
    #pragma unroll
    for (int kk=0;kk<16;kk++){
      const float4 a4 = *reinterpret_cast<const float4*>(&As[kk][ty<<2]);
      const float4 b4 = *reinterpret_cast<const float4*>(&Bs[kk][tx<<2]);
      const float av[4]={a4.x,a4.y,a4.z,a4.w};
      const float bv[4]={b4.x,b4.y,b4.z,b4.w};
      #pragma unroll
      for (int i=0;i<4;i++)
        #pragma unroll
        for (int j=0;j<4;j++)
          acc[i][j]=fmaf(av[i],bv[j],acc[i][j]);
    }
    __syncthreads();
  }
  #pragma unroll
  for (int i=0;i<4;i++){
    const int r = row0 + (ty<<2) + i;
    if (r >= M) break;
    #pragma unroll
    for (int j=0;j<4;j++){
      const int c = col0 + (tx<<2) + j;
      if (c >= N) break;
      float v = acc[i][j];
      if (bias) v += bias[c];
      const size_t idx = (size_t)r*N + c;
      if (EPI==EPI_NONE)        C[idx]=v;
      else if (EPI==EPI_SILU)   C[idx]=v*sigf(v);
    }
  }
}

#define GEMM(EPI,TB,A,B,C,bias,M,N,K) \
  gemm_k<EPI,TB><<<dim3(((N)+63)/64,((M)+63)/64),dim3(256),0,stream>>>((A),(B),(C),(bias),(M),(N),(K))

// ---------------- bf16 MFMA GEMM: 128x128 tile, BK=64 ----------------------
enum { BEPI_F32=0, BEPI_BIAS_F32, BEPI_SILU_F32, BEPI_SIG_F32, BEPI_RELU2_BF16,
       BEPI_RES_GM, BEPI_RES_GP16, BEPI_TANH_BF16 };

template<int EPI>
__global__ __launch_bounds__(256) void bgemm_k(
    const unsigned short* __restrict__ A, const unsigned short* __restrict__ B,
    void* __restrict__ Cv, const float* __restrict__ bias,
    const float* __restrict__ p1, const void* __restrict__ p2, int pstride,
    int M, int N, int K)
{
  __shared__ __align__(16) unsigned short As[128][64];
  __shared__ __align__(16) unsigned short Bs[128][64];
  const int tid = threadIdx.x;
  const int w = tid >> 6, lane = tid & 63;
  const int row0 = blockIdx.y * 128, col0 = blockIdx.x * 128;
  const int wr = w >> 1, wc = w & 1;
  const int l15 = lane & 15, l4 = lane >> 4;
  const int kkc = ((lane & 7) ^ (lane >> 3)) * 8;
  f32x4 acc[4][4] = {};
  for (int k0 = 0; k0 < K; k0 += 64) {
    #pragma unroll
    for (int i = 0; i < 4; i++) {
      const int rb = i*32 + w*8;
      const int r  = rb + (lane >> 3);
      GLDS16(A + (size_t)(row0 + r)*K + k0 + kkc, &As[rb][0]);
      GLDS16(B + (size_t)(col0 + r)*K + k0 + kkc, &Bs[rb][0]);
    }
    __syncthreads();
    #pragma unroll
    for (int ks = 0; ks < 2; ks++) {
      s16x8 af[4], bf[4];
      #pragma unroll
      for (int m = 0; m < 4; m++) {
        const int r = wr*64 + m*16 + l15;
        const int sl = (ks*4 + l4) ^ (r & 7);
        af[m] = *reinterpret_cast<const s16x8*>(&As[r][sl*8]);
      }
      #pragma unroll
      for (int n = 0; n < 4; n++) {
        const int r = wc*64 + n*16 + l15;
        const int sl = (ks*4 + l4) ^ (r & 7);
        bf[n] = *reinterpret_cast<const s16x8*>(&Bs[r][sl*8]);
      }
      #pragma unroll
      for (int m = 0; m < 4; m++)
        #pragma unroll
        for (int n = 0; n < 4; n++)
          acc[m][n] = __builtin_amdgcn_mfma_f32_16x16x32_bf16(af[m], bf[n], acc[m][n], 0, 0, 0);
    }
    __syncthreads();
  }
  float* Cf = (float*)Cv; unsigned short* Ch = (unsigned short*)Cv;
  const unsigned short* p2h = (const unsigned short*)p2;
  #pragma unroll
  for (int m = 0; m < 4; m++) {
    const int rbase = row0 + wr*64 + m*16 + (l4<<2);
    #pragma unroll
    for (int n = 0; n < 4; n++) {
      const int c = col0 + wc*64 + n*16 + l15;
      if (c >= N) continue;
      #pragma unroll
      for (int q = 0; q < 4; q++) {
        const int r = rbase + q;
        const int bb = r >> 8;
        float v = acc[m][n][q];
        const size_t idx = (size_t)r*N + c;
        if (EPI==BEPI_F32)            Cf[idx] = v;
        else if (EPI==BEPI_BIAS_F32)  Cf[idx] = v + bias[c];
        else if (EPI==BEPI_SILU_F32)  Cf[idx] = v*sigf(v);
        else if (EPI==BEPI_SIG_F32)   Cf[idx] = sigf(v);
        else if (EPI==BEPI_RELU2_BF16){ float t=fmaxf(v,0.f); Ch[idx] = f2b(t*t); }
        else if (EPI==BEPI_RES_GM)    Cf[idx] += p1[(size_t)bb*pstride + c]*v;
        else if (EPI==BEPI_RES_GP16)  Cf[idx] += p1[(size_t)bb*pstride + c]*(b2f(p2h[idx])*v);
        else if (EPI==BEPI_TANH_BF16) Ch[idx] = f2b(tanhf(v));
      }
    }
  }
}

#define BGEMM(EPI,A16,B16,Cp,bias,p1,p2,ps,M,N,K) \
  bgemm_k<EPI><<<dim3(((N)+127)/128,(M)/128),dim3(256),0,stream>>>( \
    (const unsigned short*)(A16),(const unsigned short*)(B16),(void*)(Cp),(bias),(p1),(p2),(ps),(M),(N),(K))

// ---------------- grouped bf16 GEMM (z = group id), up to 5 ----------------
// epi: 0 f32, 1 silu f32, 3 relu2 bf16, 4 bf16, 5 silu bf16, 6 tanh bf16, 7 sig bf16
struct BGrp { const unsigned short* A; const unsigned short* B; void* C;
              int epi; int N; int gx; };
struct BGrp5 { BGrp g[5]; };

__global__ __launch_bounds__(256) void bgemm_grp_k(BGrp5 G, int M, int K)
{
  const BGrp gr = G.g[blockIdx.z];
  if ((int)blockIdx.x >= gr.gx) return;
  __shared__ __align__(16) unsigned short As[128][64];
  __shared__ __align__(16) unsigned short Bs[128][64];
  const int tid = threadIdx.x;
  const int w = tid >> 6, lane = tid & 63;
  const int row0 = blockIdx.y * 128, col0 = blockIdx.x * 128;
  const int wr = w >> 1, wc = w & 1;
  const int l15 = lane & 15, l4 = lane >> 4;
  const int kkc = ((lane & 7) ^ (lane >> 3)) * 8;
  const int N = gr.N;
  f32x4 acc[4][4] = {};
  for (int k0 = 0; k0 < K; k0 += 64) {
    #pragma unroll
    for (int i = 0; i < 4; i++) {
      const int rb = i*32 + w*8;
      const int r  = rb + (lane >> 3);
      GLDS16(gr.A + (size_t)(row0 + r)*K + k0 + kkc, &As[rb][0]);
      GLDS16(gr.B + (size_t)(col0 + r)*K + k0 + kkc, &Bs[rb][0]);
    }
    __syncthreads();
    #pragma unroll
    for (int ks = 0; ks < 2; ks++) {
      s16x8 af[4], bf[4];
      #pragma unroll
      for (int m = 0; m < 4; m++) {
        const int r = wr*64 + m*16 + l15;
        const int sl = (ks*4 + l4) ^ (r & 7);
        af[m] = *reinterpret_cast<const s16x8*>(&As[r][sl*8]);
      }
      #pragma unroll
      for (int n = 0; n < 4; n++) {
        const int r = wc*64 + n*16 + l15;
        const int sl = (ks*4 + l4) ^ (r & 7);
        bf[n] = *reinterpret_cast<const s16x8*>(&Bs[r][sl*8]);
      }
      #pragma unroll
      for (int m = 0; m < 4; m++)
        #pragma unroll
        for (int n = 0; n < 4; n++)
          acc[m][n] = __builtin_amdgcn_mfma_f32_16x16x32_bf16(af[m], bf[n], acc[m][n], 0, 0, 0);
    }
    __syncthreads();
  }
  float* Cf = (float*)gr.C; unsigned short* Ch = (unsigned short*)gr.C;
  #pragma unroll
  for (int m = 0; m < 4; m++) {
    const int rbase = row0 + wr*64 + m*16 + (l4<<2);
    #pragma unroll
    for (int n = 0; n < 4; n++) {
      const int c = col0 + wc*64 + n*16 + l15;
      if (c >= N) continue;
      #pragma unroll
      for (int q = 0; q < 4; q++) {
        const int r = rbase + q;
        float v = acc[m][n][q];
        const size_t idx = (size_t)r*N + c;
        switch (gr.epi) {
          case 0: Cf[idx] = v; break;
          case 1: Cf[idx] = v*sigf(v); break;
          case 3: { float t=fmaxf(v,0.f); Ch[idx] = f2b(t*t); } break;
          case 4: Ch[idx] = f2b(v); break;
          case 5: Ch[idx] = f2b(v*sigf(v)); break;
          case 6: Ch[idx] = f2b(tanhf(v)); break;
          default: Ch[idx] = f2b(sigf(v)); break;
        }
      }
    }
  }
}

// ---------------- conv stem ----------------
__global__ __launch_bounds__(256) void conv1_k(
    const float* __restrict__ x, const float* __restrict__ w,
    const float* __restrict__ bias, float* __restrict__ out)
{
  const int blk = blockIdx.x; const int bb = blk / 384; const int oc = blk % 384;
  __shared__ __align__(16) float sIn[4*1296];
  __shared__ __align__(16) float sW[100];
  const int tid = threadIdx.x;
  for (int idx=tid; idx<4*1296; idx+=256){
    int ic = idx/1296; int rem = idx - ic*1296;
    int yy = rem/36, xx = rem - yy*36;
    int gy = yy-2, gx = xx-2;
    float v = 0.f;
    if ((unsigned)gy < 32u && (unsigned)gx < 32u)
      v = x[(((size_t)bb*4+ic)*32+gy)*32+gx];
    sIn[idx]=v;
  }
  if (tid < 100) sW[tid] = w[(size_t)oc*100 + tid];
  __syncthreads();
  const float bv = bias[oc];
  #pragma unroll
  for (int i=0;i<4;i++){
    int p = tid + 256*i; int py=p>>5, px=p&31;
    int pb = py*36+px;
    float acc = bv;
    #pragma unroll
    for (int ic=0;ic<4;ic++)
      #pragma unroll
      for (int ky=0;ky<5;ky++)
        #pragma unroll
        for (int kx=0;kx<5;kx++)
          acc = fmaf(sIn[ic*1296 + pb + ky*36+kx], sW[ic*25+ky*5+kx], acc);
    out[((size_t)(bb*384+oc))*1024 + p] = acc*sigf(acc);
  }
}

__global__ __launch_bounds__(256) void gn_stats_nchw_k(
    const float* __restrict__ h, float* __restrict__ stats)
{
  const int blk = blockIdx.x;
  const size_t base = (size_t)blk*12288;
  const int tid = threadIdx.x;
  float s=0.f, s2=0.f;
  for (int idx=tid; idx<12288; idx+=256){ float v=h[base+idx]; s+=v; s2=fmaf(v,v,s2); }
  #pragma unroll
  for (int mask=32; mask>=1; mask>>=1){ s += __shfl_xor(s,mask); s2 += __shfl_xor(s2,mask); }
  __shared__ float ps[8];
  if ((tid&63)==0){ ps[tid>>6]=s; ps[4+(tid>>6)]=s2; }
  __syncthreads();
  if (tid==0){
    s = ps[0]+ps[1]+ps[2]+ps[3]; s2 = ps[4]+ps[5]+ps[6]+ps[7];
    float mean = s*(1.f/12288.f);
    float var  = s2*(1.f/12288.f) - mean*mean;
    stats[blk*2] = mean; stats[blk*2+1] = rsqrtf(var + 1e-5f);
  }
}

__global__ void zero16_k(unsigned short* __restrict__ p)
{
  size_t i = ((size_t)blockIdx.x*256 + threadIdx.x)*8;
  *reinterpret_cast<uint4*>(p + i) = make_uint4(0u,0u,0u,0u);
}

__global__ __launch_bounds__(256) void pad_apply_k(
    const float* __restrict__ img1, const float* __restrict__ stats,
    const float* __restrict__ w, const float* __restrict__ bgn,
    unsigned short* __restrict__ pad)
{
  __shared__ float t[8][33];
  const int b = blockIdx.x >> 5, y = blockIdx.x & 31;
  const int tid = threadIdx.x;
  for (int ic0 = 0; ic0 < 384; ic0 += 8) {
    const int icr = tid >> 5, xr = tid & 31;
    t[icr][xr] = img1[(((size_t)b*384 + ic0+icr)*32 + y)*32 + xr];
    __syncthreads();
    const int xw_ = tid >> 3, icw = tid & 7;
    const int ch = ic0 + icw;
    const int g = ch / 12;
    const float mean = stats[(b*32+g)*2], rstd = stats[(b*32+g)*2+1];
    float v = (t[icw][xw_] - mean)*rstd*w[ch] + bgn[ch];
    pad[(((size_t)b*36 + y+2)*36 + (xw_+2))*384 + ch] = f2b(v);
    __syncthreads();
  }
}

__global__ __launch_bounds__(256) void wrepack_k(
    const float* __restrict__ w, unsigned short* __restrict__ wtap)
{
  __shared__ float t[9600];
  const int oc = blockIdx.x; const int tid = threadIdx.x;
  for (int i=tid;i<9600;i+=256) t[i] = w[(size_t)oc*9600 + i];
  __syncthreads();
  for (int i=tid;i<9600;i+=256){
    int tap=i/384, ic=i-tap*384;
    wtap[((size_t)tap*384 + oc)*384 + ic] = f2b(t[ic*25+tap]);
  }
}

// conv2 implicit-GEMM, ic-outer / tap-inner, bf16 out, XCD-chunk swizzle
__global__ __launch_bounds__(256) void conv2m_k(
    const unsigned short* __restrict__ inp,
    const unsigned short* __restrict__ wtap,
    const float* __restrict__ bias, unsigned short* __restrict__ out)
{
  __shared__ __align__(16) unsigned short As[128][64];
  __shared__ __align__(16) unsigned short Bs[128][64];
  const int s = (blockIdx.x % 8) * 96 + blockIdx.x / 8;
  const int ot = s / 256; const int rem = s % 256;
  const int b = rem >> 3, pt = rem & 7;
  const int y0 = pt * 4, oc0 = ot * 128;
  const int tid = threadIdx.x, w = tid>>6, lane = tid&63;
  const int wr = w>>1, wc = w&1;
  const int l15 = lane & 15, l4 = lane >> 4;
  const int kkc = ((lane&7) ^ (lane>>3)) * 8;
  f32x4 acc[4][4] = {};
  for (int ic0 = 0; ic0 < 384; ic0 += 64) {
    for (int dy = 0; dy < 5; dy++) {
      for (int dx = 0; dx < 5; dx++) {
        const int tap = dy*5 + dx;
        #pragma unroll
        for (int i = 0; i < 4; i++) {
          const int rb = i*32 + w*8;
          const int r = rb + (lane>>3);
          const int py = r >> 5, px = r & 31;
          GLDS16(inp + (((size_t)(b*36 + y0+py+dy))*36 + (px+dx))*384 + ic0 + kkc, &As[rb][0]);
          GLDS16(wtap + ((size_t)tap*384 + oc0 + r)*384 + ic0 + kkc, &Bs[rb][0]);
        }
        __syncthreads();
        #pragma unroll
        for (int ks = 0; ks < 2; ks++) {
          s16x8 af[4], bf[4];
          #pragma unroll
          for (int m = 0; m < 4; m++) {
            const int r = wr*64 + m*16 + l15;
            const int sl = (ks*4 + l4) ^ (r & 7);
            af[m] = *reinterpret_cast<const s16x8*>(&As[r][sl*8]);
          }
          #pragma unroll
          for (int n = 0; n < 4; n++) {
            const int r = wc*64 + n*16 + l15;
            const int sl = (ks*4 + l4) ^ (r & 7);
            bf[n] = *reinterpret_cast<const s16x8*>(&Bs[r][sl*8]);
          }
          #pragma unroll
          for (int m = 0; m < 4; m++)
            #pragma unroll
            for (int n = 0; n < 4; n++)
              acc[m][n] = __builtin_amdgcn_mfma_f32_16x16x32_bf16(af[m], bf[n], acc[m][n], 0, 0, 0);
        }
        __syncthreads();
      }
    }
  }
  #pragma unroll
  for (int m = 0; m < 4; m++) {
    #pragma unroll
    for (int n = 0; n < 4; n++) {
      const int oc = oc0 + wc*64 + n*16 + l15;
      const float bv = bias[oc];
      #pragma unroll
      for (int q = 0; q < 4; q++) {
        const int p = wr*64 + m*16 + (l4<<2) + q;
        const int py = p >> 5, px = p & 31;
        float v = acc[m][n][q] + bv;
        out[((size_t)b*1024 + (y0+py)*32 + px)*384 + oc] = f2b(v*sigf(v));
      }
    }
  }
}

__global__ __launch_bounds__(256) void gn_stats_nhwc_k(
    const unsigned short* __restrict__ h, float* __restrict__ stats)
{
  const int b = blockIdx.x >> 5, g = blockIdx.x & 31;
  const int tid = threadIdx.x;
  float s=0.f, s2=0.f;
  for (int idx=tid; idx<12288; idx+=256){
    int p = idx/12, c = idx - p*12;
    float v = b2f(h[((size_t)b*1024+p)*384 + g*12 + c]);
    s+=v; s2=fmaf(v,v,s2);
  }
  #pragma unroll
  for (int mask=32; mask>=1; mask>>=1){ s += __shfl_xor(s,mask); s2 += __shfl_xor(s2,mask); }
  __shared__ float ps[8];
  if ((tid&63)==0){ ps[tid>>6]=s; ps[4+(tid>>6)]=s2; }
  __syncthreads();
  if (tid==0){
    s = ps[0]+ps[1]+ps[2]+ps[3]; s2 = ps[4]+ps[5]+ps[6]+ps[7];
    float mean = s*(1.f/12288.f);
    float var  = s2*(1.f/12288.f) - mean*mean;
    stats[(b*32+g)*2] = mean; stats[(b*32+g)*2+1] = rsqrtf(var + 1e-5f);
  }
}

__global__ void patchify_gn_k(const unsigned short* __restrict__ h, const float* __restrict__ stats,
                              const float* __restrict__ w, const float* __restrict__ bgn,
                              unsigned short* __restrict__ pm)
{
  int idx = blockIdx.x*256 + threadIdx.x;
  int row = idx/1536, f = idx - row*1536;
  int c = f>>2; int p=(f>>1)&1; int q=f&1;
  int bb=row>>8; int tok=row&255; int gh=tok>>4, gw=tok&15;
  int pix = (gh*2+p)*32 + gw*2+q;
  int g = c / 12;
  float mean = stats[(bb*32+g)*2], rstd = stats[(bb*32+g)*2+1];
  float v = (b2f(h[((size_t)bb*1024 + pix)*384 + c]) - mean)*rstd*w[c] + bgn[c];
  pm[idx] = f2b(v);
}

// ---------------- conditioning / misc ----------------
__global__ void temb_in_k(const float* __restrict__ t, float* __restrict__ out)
{
  int bb = blockIdx.x; int i = threadIdx.x;
  float fr = expf(-logf(10000.f) * (float)i / 128.f);
  float ang = t[bb]*fr;
  out[bb*256+i]     = cosf(ang);
  out[bb*256+128+i] = sinf(ang);
}

__global__ void siluc_k(const float* __restrict__ t2, const float* __restrict__ ytab,
                        const int* __restrict__ y, float* __restrict__ sc)
{
  int bb = blockIdx.x; int tid = threadIdx.x;
  int cls = y[bb];
  for (int c=tid; c<768; c+=256){
    float v = t2[bb*768+c] + ytab[(size_t)cls*768+c];
    sc[bb*768+c] = v*sigf(v);
  }
}

__global__ __launch_bounds__(256) void ln_mod_k(
    const float* __restrict__ in, float* __restrict__ out,
    const float* __restrict__ w, const float* __restrict__ b,
    const float* __restrict__ mod, int mstride, int sh_off, int sc_off, float eps)
{
  const int m = blockIdx.x; const int tid = threadIdx.x;
  const size_t base = (size_t)m*768;
  float v0=in[base+tid], v1=in[base+tid+256], v2=in[base+tid+512];
  float s = v0+v1+v2;
  float s2 = fmaf(v0,v0,fmaf(v1,v1,v2*v2));
  #pragma unroll
  for (int mask=32; mask>=1; mask>>=1){ s += __shfl_xor(s,mask); s2 += __shfl_xor(s2,mask); }
  __shared__ float ps[8];
  if ((tid&63)==0){ ps[tid>>6]=s; ps[4+(tid>>6)]=s2; }
  __syncthreads();
  s = ps[0]+ps[1]+ps[2]+ps[3]; s2 = ps[4]+ps[5]+ps[6]+ps[7];
  const float mean = s*(1.f/768.f);
  const float var  = s2*(1.f/768.f) - mean*mean;
  const float rstd = rsqrtf(var + eps);
  const int bb = m >> 8;
  #pragma unroll
  for (int k=0;k<3;k++){
    const int c = tid + k*256;
    float v = (k==0)?v0:((k==1)?v1:v2);
    float xh = (v-mean)*rstd;
    if (w) xh = fmaf(xh, w[c], b[c]);
    if (mod){
      float scv = mod[(size_t)bb*mstride + sc_off + c];
      float shv = mod[(size_t)bb*mstride + sh_off + c];
      xh = fmaf(xh, 1.f+scv, shv);
    }
    out[base+c] = xh;
  }
}

// fused LN+mod+token-shift (timemix); hmod/xx bf16
__global__ __launch_bounds__(256) void ln_shift_tm_k(
    const float* __restrict__ xs, const float* __restrict__ w, const float* __restrict__ b,
    const float* __restrict__ mod, const float* __restrict__ maa0,
    unsigned short* __restrict__ hmod16, unsigned short* __restrict__ xx16,
    unsigned short* __restrict__ xxx16)
{
  const int m = blockIdx.x, tid = threadIdx.x;
  const size_t base = (size_t)m*768;
  const int t = m & 255, bb = m >> 8;
  float c0=xs[base+tid], c1=xs[base+tid+256], c2=xs[base+tid+512];
  float p0=0.f,p1=0.f,p2=0.f;
  if (t) { p0=xs[base-768+tid]; p1=xs[base-512+tid]; p2=xs[base-256+tid]; }
  float sc_=c0+c1+c2, sc2=fmaf(c0,c0,fmaf(c1,c1,c2*c2));
  float sp_=p0+p1+p2, sp2=fmaf(p0,p0,fmaf(p1,p1,p2*p2));
  #pragma unroll
  for (int mask=32; mask>=1; mask>>=1){
    sc_+=__shfl_xor(sc_,mask); sc2+=__shfl_xor(sc2,mask);
    sp_+=__shfl_xor(sp_,mask); sp2+=__shfl_xor(sp2,mask);
  }
  __shared__ float ps[16];
  if ((tid&63)==0){ int wv=tid>>6; ps[wv]=sc_; ps[4+wv]=sc2; ps[8+wv]=sp_; ps[12+wv]=sp2; }
  __syncthreads();
  sc_=ps[0]+ps[1]+ps[2]+ps[3]; sc2=ps[4]+ps[5]+ps[6]+ps[7];
  sp_=ps[8]+ps[9]+ps[10]+ps[11]; sp2=ps[12]+ps[13]+ps[14]+ps[15];
  const float mc = sc_*(1.f/768.f), rc = rsqrtf(sc2*(1.f/768.f)-mc*mc + 1e-5f);
  const float mp = sp_*(1.f/768.f), rp = rsqrtf(sp2*(1.f/768.f)-mp*mp + 1e-5f);
  #pragma unroll
  for (int k=0;k<3;k++){
    const int c = tid + k*256;
    const float scv = mod[(size_t)bb*55296 + 768 + c];
    const float shv = mod[(size_t)bb*55296 + c];
    float cv = (k==0)?c0:((k==1)?c1:c2);
    float h = fmaf((cv-mc)*rc, w[c], b[c]);
    h = fmaf(h, 1.f+scv, shv);
    float pv = 0.f;
    if (t) {
      float pk = (k==0)?p0:((k==1)?p1:p2);
      pv = fmaf((pk-mp)*rp, w[c], b[c]);
      pv = fmaf(pv, 1.f+scv, shv);
    }
    const float d = pv - h;
    hmod16[base+c] = f2b(h);
    xx16[base+c] = f2b(d);
    xxx16[base+c] = f2b(fmaf(d, maa0[c], h));
  }
}

// fused LN+mod+token-shift (chanmix)
__global__ __launch_bounds__(256) void ln_shift_cm_k(
    const float* __restrict__ xs, const float* __restrict__ w, const float* __restrict__ b,
    const float* __restrict__ mod, const float* __restrict__ fmaa,
    unsigned short* __restrict__ xk16, unsigned short* __restrict__ xr16)
{
  const int m = blockIdx.x, tid = threadIdx.x;
  const size_t base = (size_t)m*768;
  const int t = m & 255, bb = m >> 8;
  float c0=xs[base+tid], c1=xs[base+tid+256], c2=xs[base+tid+512];
  float p0=0.f,p1=0.f,p2=0.f;
  if (t) { p0=xs[base-768+tid]; p1=xs[base-512+tid]; p2=xs[base-256+tid]; }
  float sc_=c0+c1+c2, sc2=fmaf(c0,c0,fmaf(c1,c1,c2*c2));
  float sp_=p0+p1+p2, sp2=fmaf(p0,p0,fmaf(p1,p1,p2*p2));
  #pragma unroll
  for (int mask=32; mask>=1; mask>>=1){
    sc_+=__shfl_xor(sc_,mask); sc2+=__shfl_xor(sc2,mask);
    sp_+=__shfl_xor(sp_,mask); sp2+=__shfl_xor(sp2,mask);
  }
  __shared__ float ps[16];
  if ((tid&63)==0){ int wv=tid>>6; ps[wv]=sc_; ps[4+wv]=sc2; ps[8+wv]=sp_; ps[12+wv]=sp2; }
  __syncthreads();
  sc_=ps[0]+ps[1]+ps[2]+ps[3]; sc2=ps[4]+ps[5]+ps[6]+ps[7];
  sp_=ps[8]+ps[9]+ps[10]+ps[11]; sp2=ps[12]+ps[13]+ps[14]+ps[15];
  const float mc = sc_*(1.f/768.f), rc = rsqrtf(sc2*(1.f/768.f)-mc*mc + 1e-5f);
  const float mp = sp_*(1.f/768.f), rp = rsqrtf(sp2*(1.f/768.f)-mp*mp + 1e-5f);
  #pragma unroll
  for (int k=0;k<3;k++){
    const int c = tid + k*256;
    const float scv = mod[(size_t)bb*55296 + 3072 + c];
    const float shv = mod[(size_t)bb*55296 + 2304 + c];
    float cv = (k==0)?c0:((k==1)?c1:c2);
    float h = fmaf((cv-mc)*rc, w[c], b[c]);
    h = fmaf(h, 1.f+scv, shv);
    float pv = 0.f;
    if (t) {
      float pk = (k==0)?p0:((k==1)?p1:p2);
      pv = fmaf((pk-mp)*rp, w[c], b[c]);
      pv = fmaf(pv, 1.f+scv, shv);
    }
    const float d = pv - h;
    xk16[base+c] = f2b(fmaf(d, fmaa[c], h));
    xr16[base+c] = f2b(fmaf(d, fmaa[768+c], h));
  }
}

// 16 rows/block (512 blocks); tm_w2 read as bf16
__global__ __launch_bounds__(256) void five_mix_k(
    const unsigned short* __restrict__ mix16, const unsigned short* __restrict__ w2,
    const unsigned short* __restrict__ hmod16, const unsigned short* __restrict__ xx16,
    const float* __restrict__ maa15,
    unsigned short* __restrict__ xw, unsigned short* __restrict__ xk,
    unsigned short* __restrict__ xv, unsigned short* __restrict__ xr,
    unsigned short* __restrict__ xg)
{
  __shared__ __align__(16) float smix[16][160];
  const int m0 = blockIdx.x * 16;
  const int tid = threadIdx.x;
  for (int idx=tid; idx<16*160; idx+=256){
    int r = idx/160, d = idx - r*160;
    smix[r][d] = b2f(mix16[(size_t)(m0+r)*160 + d]);
  }
  __syncthreads();
  #pragma unroll 1
  for (int cc=0; cc<3; cc++){
    const int c = tid + cc*256;
    float hv[16], xv_[16];
    #pragma unroll
    for (int r=0;r<16;r++){
      size_t id=(size_t)(m0+r)*768+c;
      hv[r]=b2f(hmod16[id]); xv_[r]=b2f(xx16[id]);
    }
    #pragma unroll 1
    for (int f=0; f<5; f++){
      float acc[16];
      const float base = maa15[f*768 + c];
      #pragma unroll
      for (int r=0;r<16;r++) acc[r]=base;
      #pragma unroll 1
      for (int d4=0; d4<8; d4++){
        float wv[4];
        #pragma unroll
        for (int q=0;q<4;q++) wv[q] = b2f(w2[(size_t)(f*32+d4*4+q)*768 + c]);
        #pragma unroll
        for (int r=0;r<16;r++){
          const float4 mv = *reinterpret_cast<const float4*>(&smix[r][f*32+d4*4]);
          acc[r] = fmaf(mv.x,wv[0],fmaf(mv.y,wv[1],fmaf(mv.z,wv[2],fmaf(mv.w,wv[3],acc[r]))));
        }
      }
      #pragma unroll
      for (int r=0;r<16;r++){
        float val = fmaf(xv_[r], acc[r], hv[r]);
        size_t id = (size_t)(m0+r)*768+c;
        if (f==0) xw[id]=f2b(val);
        else if (f==1) xk[id]=f2b(val);
        else if (f==2) xv[id]=f2b(val);
        else if (f==3) xr[id]=f2b(val);
        else           xg[id]=f2b(val);
      }
    }
  }
}

// ---------------- chunked MFMA WKV (fused wd-decay + head-GN + gate) --------
// wd[t][j] = exp(-exp( (wt16 @ td2)[t][j] + tdv[j] )) computed per chunk via
// 4 MFMAs from L2-resident wt16 (8192x64) and the block's 64x64 td2 slice.
__global__ __launch_bounds__(256) void wkv_k(
    const unsigned short* __restrict__ rg, const unsigned short* __restrict__ kg,
    const unsigned short* __restrict__ vg, const unsigned short* __restrict__ gg,
    const unsigned short* __restrict__ wtp, const unsigned short* __restrict__ td2w,
    const float* __restrict__ tdvp, const float* __restrict__ u,
    const float* __restrict__ lnxw, const float* __restrict__ lnxb,
    unsigned short* __restrict__ out16)
{
  const int bh = blockIdx.x; const int b = bh/12, h = bh%12;
  const int tid = threadIdx.x;
  const int w = tid >> 6, lane = tid & 63;
  const int l4 = lane >> 4, l15 = lane & 15;
  __shared__ __align__(16) unsigned short r16s[32][64], k16s[32][64], v16s[32][64], g16s[32][64];
  __shared__ __align__(16) float wds[32][64];
  __shared__ __align__(16) float Wl[33][64];
  __shared__ __align__(16) unsigned short rr16[32][64], kk16[32][64];
  __shared__ __align__(16) unsigned short kk2T[64][32], vT[64][32];
  __shared__ __align__(16) unsigned short S16T[64][64];
  __shared__ __align__(16) unsigned short A16[32][32];
  __shared__ float diag[32], ypsum[32][4], ypsq[32][4];

  reinterpret_cast<uint4*>(&S16T[0][0])[tid] = make_uint4(0,0,0,0);
  reinterpret_cast<uint4*>(&S16T[0][0])[256+tid] = make_uint4(0,0,0,0);

  const float u_lane = u[h*64 + lane];
  const int jj = w*16 + l15;
  const float lw = lnxw[h*64 + jj], lb = lnxb[h*64 + jj];
  const size_t gb = (size_t)(b*256)*768 + h*64;

  // wd GEMM constants: B-fragments from td2 slice + tdv
  s16x8 wdb[2];
  #pragma unroll
  for (int ks=0; ks<2; ks++)
    wdb[ks] = *reinterpret_cast<const s16x8*>(td2w + (size_t)(h*64 + jj)*64 + (ks*4+l4)*8);
  const float tdv_r = tdvp[h*64 + jj];
  const size_t wtbase = (size_t)(b*256)*64;

  const int st_t = tid >> 3, st_i = (tid & 7) * 8;
  uint4 pr, pk, pv, pg;

#define WKV_LOADC(c_) { \
    const size_t tb = gb + (size_t)((c_)*32 + st_t)*768 + st_i; \
    pr = *reinterpret_cast<const uint4*>(rg + tb); \
    pk = *reinterpret_cast<const uint4*>(kg + tb); \
    pv = *reinterpret_cast<const uint4*>(vg + tb); \
    pg = *reinterpret_cast<const uint4*>(gg + tb); }
#define WKV_STAGE() { \
    *reinterpret_cast<uint4*>(&r16s[st_t][st_i]) = pr; \
    *reinterpret_cast<uint4*>(&k16s[st_t][st_i]) = pk; \
    *reinterpret_cast<uint4*>(&v16s[st_t][st_i]) = pv; \
    *reinterpret_cast<uint4*>(&g16s[st_t][st_i]) = pg; }

  f32x4 S_acc[4] = {};

  WKV_LOADC(0);
  WKV_STAGE();
  __syncthreads();

  #pragma unroll 1
  for (int c = 0; c < 8; ++c) {
    // ---- wd tile for this chunk (all waves; wave w owns cols 16w..16w+15) --
    {
      f32x4 wdacc[2] = {};
      #pragma unroll
      for (int m=0;m<2;m++)
        #pragma unroll
        for (int ks=0;ks<2;ks++){
          s16x8 wa = *reinterpret_cast<const s16x8*>(
              wtp + wtbase + (size_t)(c*32 + m*16 + l15)*64 + (ks*4+l4)*8);
          wdacc[m] = __builtin_amdgcn_mfma_f32_16x16x32_bf16(wa, wdb[ks], wdacc[m], 0,0,0);
        }
      #pragma unroll
      for (int m=0;m<2;m++)
        #pragma unroll
        for (int q=0;q<4;q++)
          wds[m*16 + l4*4 + q][jj] = expf(-expf(wdacc[m][q] + tdv_r));
    }
    __syncthreads();   // wds complete
    if (w == 0) {
      float wv[32];
      #pragma unroll
      for (int t=0;t<32;t++) wv[t] = wds[t][lane];
      float P = 1.f;
      Wl[0][lane] = 1.f;
      #pragma unroll
      for (int t=0;t<32;t++){ P *= wv[t]; Wl[t+1][lane] = P; }
    }
    __syncthreads();
    {
      const int t = st_t, i0 = st_i;
      s16x8 rv = *reinterpret_cast<const s16x8*>(&r16s[t][i0]);
      s16x8 kv = *reinterpret_cast<const s16x8*>(&k16s[t][i0]);
      s16x8 vv = *reinterpret_cast<const s16x8*>(&v16s[t][i0]);
      float4 wa0 = *reinterpret_cast<const float4*>(&Wl[t][i0]);
      float4 wa1 = *reinterpret_cast<const float4*>(&Wl[t][i0+4]);
      float4 wb0 = *reinterpret_cast<const float4*>(&Wl[t+1][i0]);
      float4 wb1 = *reinterpret_cast<const float4*>(&Wl[t+1][i0+4]);
      float4 wf0 = *reinterpret_cast<const float4*>(&Wl[32][i0]);
      float4 wf1 = *reinterpret_cast<const float4*>(&Wl[32][i0+4]);
      float wt_[8] = {wa0.x,wa0.y,wa0.z,wa0.w,wa1.x,wa1.y,wa1.z,wa1.w};
      float wt1[8] = {wb0.x,wb0.y,wb0.z,wb0.w,wb1.x,wb1.y,wb1.z,wb1.w};
      float w32[8] = {wf0.x,wf0.y,wf0.z,wf0.w,wf1.x,wf1.y,wf1.z,wf1.w};
      s16x8 rro, kko;
      #pragma unroll
      for (int e=0;e<8;e++){
        const int i = i0 + e;
        float rf = b2f((unsigned short)rv[e]) * wt_[e];
        float kf = b2f((unsigned short)kv[e]) / wt1[e];
        rro[e] = (short)f2b(rf);
        kko[e] = (short)f2b(kf);
        kk2T[i][(((t>>3)^(i&3))<<3) + (t&7)] = f2b(kf * w32[e]);
        vT[i][(((t>>3)^(i&3))<<3) + (t&7)] = (unsigned short)vv[e];
      }
      const int sc_ = ((i0>>3)^(t&7))<<3;
      *reinterpret_cast<s16x8*>(&rr16[t][sc_]) = rro;
      *reinterpret_cast<s16x8*>(&kk16[t][sc_]) = kko;
      #pragma unroll
      for (int tt=0;tt<8;tt++){
        const int td = w*8 + tt;
        float p = b2f(r16s[td][lane]) * u_lane * b2f(k16s[td][lane]);
        #pragma unroll
        for (int mask=32; mask>=1; mask>>=1) p += __shfl_xor(p, mask);
        if (lane==0) diag[td] = p;
      }
    }
    __syncthreads();
    if (c < 7) WKV_LOADC(c+1);
    f32x4 Y[2] = {};
    s16x8 rrf[2][2];
    #pragma unroll
    for (int m=0;m<2;m++)
      #pragma unroll
      for (int kt=0;kt<2;kt++){
        const int row = m*16 + l15;
        rrf[m][kt] = *reinterpret_cast<const s16x8*>(&rr16[row][(((kt*4+l4)^(row&7))<<3)]);
      }
    #pragma unroll
    for (int m=0;m<2;m++)
      #pragma unroll
      for (int kt=0;kt<2;kt++){
        s16x8 sf = *reinterpret_cast<const s16x8*>(&S16T[jj][(((kt*4+l4)^(jj&7))<<3)]);
        Y[m] = __builtin_amdgcn_mfma_f32_16x16x32_bf16(rrf[m][kt], sf, Y[m], 0,0,0);
      }
    s16x8 vtf = *reinterpret_cast<const s16x8*>(&vT[jj][((l4^(jj&3))<<3)]);
    #pragma unroll
    for (int m=0;m<4;m++){
      const int row = m*16 + l15;
      s16x8 k2f = *reinterpret_cast<const s16x8*>(&kk2T[row][((l4^(row&3))<<3)]);
      #pragma unroll
      for (int q=0;q<4;q++) S_acc[m][q] *= Wl[32][m*16 + l4*4 + q];
      S_acc[m] = __builtin_amdgcn_mfma_f32_16x16x32_bf16(k2f, vtf, S_acc[m], 0,0,0);
    }
    if (w == 0) {
      f32x4 Aac[2][2] = {};
      #pragma unroll
      for (int m=0;m<2;m++)
        #pragma unroll
        for (int n=0;n<2;n++)
          #pragma unroll
          for (int kt=0;kt<2;kt++){
            const int srow = n*16 + l15;
            s16x8 kf = *reinterpret_cast<const s16x8*>(&kk16[srow][(((kt*4+l4)^(srow&7))<<3)]);
            Aac[m][n] = __builtin_amdgcn_mfma_f32_16x16x32_bf16(rrf[m][kt], kf, Aac[m][n], 0,0,0);
          }
      #pragma unroll
      for (int m=0;m<2;m++)
        #pragma unroll
        for (int n=0;n<2;n++)
          #pragma unroll
          for (int q=0;q<4;q++){
            const int t = m*16 + l4*4 + q;
            const int s = n*16 + l15;
            float av = Aac[m][n][q];
            av = (s < t) ? av : ((s == t) ? diag[t] : 0.f);
            A16[t][(((s>>3)^(t&3))<<3) + (s&7)] = f2b(av);
          }
    }
    #pragma unroll
    for (int m=0;m<4;m++)
      #pragma unroll
      for (int q=0;q<4;q++){
        const int i = m*16 + l4*4 + q;
        S16T[jj][(((i>>3)^(jj&7))<<3) + (i&7)] = f2b(S_acc[m][q]);
      }
    __syncthreads();
    #pragma unroll
    for (int m=0;m<2;m++){
      const int row = m*16 + l15;
      s16x8 af = *reinterpret_cast<const s16x8*>(&A16[row][((l4^(row&3))<<3)]);
      Y[m] = __builtin_amdgcn_mfma_f32_16x16x32_bf16(af, vtf, Y[m], 0,0,0);
    }
    #pragma unroll
    for (int m=0;m<2;m++)
      #pragma unroll
      for (int q=0;q<4;q++){
        float s1 = Y[m][q], s2 = s1*s1;
        #pragma unroll
        for (int mask=8; mask>=1; mask>>=1){ s1 += __shfl_xor(s1,mask); s2 += __shfl_xor(s2,mask); }
        if (l15==0){ const int t = m*16 + l4*4 + q; ypsum[t][w]=s1; ypsq[t][w]=s2; }
      }
    __syncthreads();
    #pragma unroll
    for (int m=0;m<2;m++)
      #pragma unroll
      for (int q=0;q<4;q++){
        const int t = m*16 + l4*4 + q;
        float s1 = ypsum[t][0]+ypsum[t][1]+ypsum[t][2]+ypsum[t][3];
        float s2 = ypsq[t][0]+ypsq[t][1]+ypsq[t][2]+ypsq[t][3];
        float mean = s1*(1.f/64.f);
        float var  = s2*(1.f/64.f) - mean*mean;
        float xh = (Y[m][q]-mean)*rsqrtf(var + 6.4e-4f);
        float o = fmaf(xh, lw, lb) * b2f(g16s[t][jj]);
        out16[gb + (size_t)(c*32+t)*768 + jj] = f2b(o);
      }
    if (c < 7) {
      __syncthreads();
      WKV_STAGE();
      __syncthreads();
    }
  }
#undef WKV_LOADC
#undef WKV_STAGE
}

__global__ void unpatch_k(const float* __restrict__ po, float* __restrict__ out)
{
  int idx = blockIdx.x*256 + threadIdx.x;
  int xq=idx&31; int yy=(idx>>5)&31; int ch=(idx>>10)&3; int bb=idx>>12;
  int gh=yy>>1, p=yy&1, gw=xq>>1, q=xq&1;
  out[idx] = po[((size_t)(bb*256+gh*16+gw))*16 + p*8+q*4+ch];
}

// ---------------- fp32 -> bf16 conversions / repacks ----------------
__global__ void f2b_k(const float* __restrict__ s, unsigned short* __restrict__ d)
{
  size_t i = ((size_t)blockIdx.x*256 + threadIdx.x)*8;
  float4 a = *reinterpret_cast<const float4*>(s+i);
  float4 b = *reinterpret_cast<const float4*>(s+i+4);
  s16x8 o;
  o[0]=(short)f2b(a.x); o[1]=(short)f2b(a.y); o[2]=(short)f2b(a.z); o[3]=(short)f2b(a.w);
  o[4]=(short)f2b(b.x); o[5]=(short)f2b(b.y); o[6]=(short)f2b(b.z); o[7]=(short)f2b(b.w);
  *reinterpret_cast<s16x8*>(d + i) = o;
}

// merged per-layer weight convert + mix/decay repack + tm_w2 bf16.
// blocks [0,3744): bulk convert r,k,v,o,g,fr (589824 ea), fk, fv (2064384 ea)
// blocks [3744,5568): tm_w1->(256,768), td_w1->(128,768), td_w2->(768,64), tm_w2 flat
__global__ void f2bw_layer_k(
    const float* __restrict__ r_, const float* __restrict__ k_, const float* __restrict__ v_,
    const float* __restrict__ o_, const float* __restrict__ g_, const float* __restrict__ fr_,
    const float* __restrict__ fk_, const float* __restrict__ fv_,
    const float* __restrict__ tm1, const float* __restrict__ td1, const float* __restrict__ td2,
    const float* __restrict__ tm2, unsigned short* __restrict__ dst)
{
  if (blockIdx.x < 3744) {
    size_t i = ((size_t)blockIdx.x*256 + threadIdx.x)*8;
    const float* s; size_t off;
    if (i < 3538944) {
      unsigned seg = (unsigned)(i / 589824u); off = i - (size_t)seg*589824u;
      s = seg==0?r_:seg==1?k_:seg==2?v_:seg==3?o_:seg==4?g_:fr_;
    } else if (i < 5603328) { s = fk_; off = i - 3538944; }
    else                    { s = fv_; off = i - 5603328; }
    float4 a = *reinterpret_cast<const float4*>(s+off);
    float4 b = *reinterpret_cast<const float4*>(s+off+4);
    s16x8 o;
    o[0]=(short)f2b(a.x); o[1]=(short)f2b(a.y); o[2]=(short)f2b(a.z); o[3]=(short)f2b(a.w);
    o[4]=(short)f2b(b.x); o[5]=(short)f2b(b.y); o[6]=(short)f2b(b.z); o[7]=(short)f2b(b.w);
    *reinterpret_cast<s16x8*>(dst + i) = o;
  } else {
    int idx = (blockIdx.x-3744)*256 + threadIdx.x;   // 0..466943
    unsigned short* rp = dst + 7667712;
    if (idx < 196608) {
      int n = idx/768, k = idx - n*768;
      rp[idx] = (n<160) ? f2b(tm1[(size_t)k*160 + n]) : (unsigned short)0;
    } else if (idx < 294912) {
      int i = idx-196608; int n = i/768, k = i - n*768;
      rp[idx] = (n<64) ? f2b(td1[(size_t)k*64 + n]) : (unsigned short)0;
    } else if (idx < 344064) {
      int i = idx-294912; int n = i/64, k = i - n*64;
      rp[idx] = f2b(td2[(size_t)k*768 + n]);
    } else {
      int i = idx-344064;                    // 0..122879, flat (5,32,768)
      rp[idx] = f2b(tm2[i]);
    }
  }
}

// ---------------------------------------------------------------------------
extern "C" void kernel_launch(void* const* d_in, const int* in_sizes, int n_in,
                              void* d_out, int out_size, void* d_ws, size_t ws_size,
                              hipStream_t stream)
{
  const float* x_in  = (const float*)d_in[0];
  const float* t_in  = (const float*)d_in[1];
  const int*   y_in  = (const int*)  d_in[2];
  const float* c1w   = (const float*)d_in[3];
  const float* c1b   = (const float*)d_in[4];
  const float* gn1w  = (const float*)d_in[5];
  const float* gn1b  = (const float*)d_in[6];
  const float* c2w   = (const float*)d_in[7];
  const float* c2b   = (const float*)d_in[8];
  const float* gn2w  = (const float*)d_in[9];
  const float* gn2b  = (const float*)d_in[10];
  const float* xew   = (const float*)d_in[11];
  const float* xeb   = (const float*)d_in[12];
  const float* tew1  = (const float*)d_in[13];
  const float* teb1  = (const float*)d_in[14];
  const float* tew2  = (const float*)d_in[15];
  const float* teb2  = (const float*)d_in[16];
  const float* ytab  = (const float*)d_in[17];
  const float* ln0w  = (const float*)d_in[18];
  const float* ln0b  = (const float*)d_in[19];
  const float* ln1w  = (const float*)d_in[20];
  const float* ln1b  = (const float*)d_in[21];
  const float* ln2w  = (const float*)d_in[22];
  const float* ln2b  = (const float*)d_in[23];
  const float* amaa  = (const float*)d_in[24];
  const float* tmw1  = (const float*)d_in[25];
  const float* tmw2  = (const float*)d_in[26];
  const float* tdv   = (const float*)d_in[27];
  const float* tdw1  = (const float*)d_in[28];
  const float* tdw2  = (const float*)d_in[29];
  const float* faa   = (const float*)d_in[30];
  const float* rw    = (const float*)d_in[31];
  const float* kw    = (const float*)d_in[32];
  const float* vw    = (const float*)d_in[33];
  const float* ow    = (const float*)d_in[34];
  const float* gw    = (const float*)d_in[35];
  const float* lnxw  = (const float*)d_in[36];
  const float* lnxb  = (const float*)d_in[37];
  const float* fmaa  = (const float*)d_in[38];
  const float* fkw   = (const float*)d_in[39];
  const float* frw   = (const float*)d_in[40];
  const float* fvw   = (const float*)d_in[41];
  const float* adaw  = (const float*)d_in[42];
  const float* adab  = (const float*)d_in[43];
  const float* flaw  = (const float*)d_in[44];
  const float* flab  = (const float*)d_in[45];
  const float* flw   = (const float*)d_in[46];
  const float* flb   = (const float*)d_in[47];

  float* Wf = (float*)d_ws;
  float* xs   = Wf+O_XS;   float* hmodf = Wf+O_HMOD;
  float* ada  = Wf+O_ADA;  float* fla  = Wf+O_FLA;
  float* t2   = Wf+O_T2;   float* sc   = Wf+O_SC;
  float* ti   = Wf+O_TI;   float* t1   = Wf+O_T1;
  float* st1  = Wf+O_ST1;  float* st2  = Wf+O_ST2;
  unsigned short* xew16 = (unsigned short*)(Wf+O_XEW16);
  unsigned short* wl16  = (unsigned short*)(Wf+O_WL16);
  unsigned short* hmod16 = (unsigned short*)(Wf+O_HMOD);
  float* big = Wf+O_BIG;
  unsigned short* xx16  = (unsigned short*)(big+L_XX);
  unsigned short* rb16  = (unsigned short*)(big+L_XXX);
  unsigned short* kb16  = (unsigned short*)(big+L_KB);
  unsigned short* vb16  = (unsigned short*)(big+L_VB);
  unsigned short* gb16  = (unsigned short*)(big+L_GB);
  unsigned short* xw16  = (unsigned short*)(big+L_XW);
  unsigned short* xxx16 = (unsigned short*)(big+L_XXX);
  unsigned short* mixb16= (unsigned short*)(big+L_MIXB);
  unsigned short* wt16  = (unsigned short*)(big+L_WT);
  unsigned short* xk16 = (unsigned short*)(big+L_XK16);
  unsigned short* xv16 = (unsigned short*)(big+L_XV16);
  unsigned short* xr16 = (unsigned short*)(big+L_XR16);
  unsigned short* xg16 = (unsigned short*)(big+L_XG16);
  unsigned short* gnh16 = (unsigned short*)(big+L_GNH16);
  unsigned short* kbig16 = (unsigned short*)(big+L_KBIG16);
  float* img1 = big+S_IMG1;
  unsigned short* img2_16 = (unsigned short*)(big+S_IMG2);
  unsigned short* pad16  = (unsigned short*)(big+S_PAD16);
  unsigned short* wtap16 = (unsigned short*)(big+S_WTAP16);
  unsigned short* pm16   = (unsigned short*)(big+S_PM16);
  float* pout = big+L_MIXB;
  unsigned short* dr  = wl16;
  unsigned short* dk  = wl16 + 589824;
  unsigned short* dv  = wl16 + 1179648;
  unsigned short* do_ = wl16 + 1769472;
  unsigned short* dg  = wl16 + 2359296;
  unsigned short* dfr = wl16 + 2949120;
  unsigned short* dfk = wl16 + 3538944;
  unsigned short* dfv = wl16 + 5603328;
  unsigned short* dtm1t = wl16 + 7667712;
  unsigned short* dtd1t = wl16 + 7864320;
  unsigned short* dtd2t = wl16 + 7962624;   // (768 x 64)
  unsigned short* dtmw2 = wl16 + 8011776;   // (5,32,768) bf16

  // ---- conv stem ----
  conv1_k<<<dim3(32*384),dim3(256),0,stream>>>(x_in, c1w, c1b, img1);
  gn_stats_nchw_k<<<dim3(1024),dim3(256),0,stream>>>(img1, st1);
  zero16_k<<<dim3(7776),dim3(256),0,stream>>>(pad16);
  pad_apply_k<<<dim3(1024),dim3(256),0,stream>>>(img1, st1, gn1w, gn1b, pad16);
  wrepack_k<<<dim3(384),dim3(256),0,stream>>>(c2w, wtap16);
  conv2m_k<<<dim3(768),dim3(256),0,stream>>>(pad16, wtap16, c2b, img2_16);
  gn_stats_nhwc_k<<<dim3(1024),dim3(256),0,stream>>>(img2_16, st2);
  patchify_gn_k<<<dim3(49152),dim3(256),0,stream>>>(img2_16, st2, gn2w, gn2b, pm16);
  f2b_k<<<dim3(576),dim3(256),0,stream>>>(xew, xew16);
  BGEMM(BEPI_BIAS_F32, pm16, xew16, xs, xeb, nullptr,nullptr,0, 8192,768,1536);

  // ---- conditioning ----
  temb_in_k<<<dim3(32),dim3(128),0,stream>>>(t_in, ti);
  GEMM(EPI_SILU,true, ti, tew1, t1, teb1, 32,768,256);
  GEMM(EPI_NONE,true, t1, tew2, t2, teb2, 32,768,768);
  siluc_k<<<dim3(32),dim3(256),0,stream>>>(t2, ytab, y_in, sc);
  GEMM(EPI_NONE,true, sc, adaw, ada, adab, 32,55296,768);
  GEMM(EPI_NONE,true, sc, flaw, fla, flab, 32,1536,768);

  // ---- ln0 ----
  ln_mod_k<<<dim3(8192),dim3(256),0,stream>>>(xs, xs, ln0w, ln0b, nullptr, 0,0,0, 1e-5f);

  for (int l=0; l<12; l++){
    const float* adal = ada + (size_t)l*4608;
    f2bw_layer_k<<<dim3(5568),dim3(256),0,stream>>>(
        rw+(size_t)l*589824, kw+(size_t)l*589824, vw+(size_t)l*589824,
        ow+(size_t)l*589824, gw+(size_t)l*589824, frw+(size_t)l*589824,
        fkw+(size_t)l*2064384, fvw+(size_t)l*2064384,
        tmw1+(size_t)l*122880, tdw1+(size_t)l*49152, tdw2+(size_t)l*49152,
        tmw2+(size_t)l*122880, wl16);
    // --- timemix ---
    ln_shift_tm_k<<<dim3(8192),dim3(256),0,stream>>>(
        xs, ln1w+(size_t)l*768, ln1b+(size_t)l*768, adal, amaa+(size_t)l*4608,
        hmod16, xx16, xxx16);
    BGEMM(BEPI_TANH_BF16, xxx16, dtm1t, mixb16, nullptr,nullptr,nullptr,0, 8192,160,768);
    five_mix_k<<<dim3(512),dim3(256),0,stream>>>(mixb16, dtmw2, hmod16, xx16,
                                                 amaa+(size_t)l*4608+768, xw16,xk16,xv16,xr16,xg16);
    {
      BGrp5 G;
      G.g[0].A=xr16; G.g[0].B=dr;    G.g[0].C=rb16; G.g[0].epi=4; G.g[0].N=768; G.g[0].gx=6;
      G.g[1].A=xk16; G.g[1].B=dk;    G.g[1].C=kb16; G.g[1].epi=4; G.g[1].N=768; G.g[1].gx=6;
      G.g[2].A=xv16; G.g[2].B=dv;    G.g[2].C=vb16; G.g[2].epi=4; G.g[2].N=768; G.g[2].gx=6;
      G.g[3].A=xg16; G.g[3].B=dg;    G.g[3].C=gb16; G.g[3].epi=5; G.g[3].N=768; G.g[3].gx=6;
      G.g[4].A=xw16; G.g[4].B=dtd1t; G.g[4].C=wt16; G.g[4].epi=6; G.g[4].N=64;  G.g[4].gx=1;
      bgemm_grp_k<<<dim3(6,64,5),dim3(256),0,stream>>>(G, 8192, 768);
    }
    wkv_k<<<dim3(384),dim3(256),0,stream>>>(rb16, kb16, vb16, gb16, wt16, dtd2t,
                                            tdv+(size_t)l*768, faa+(size_t)l*768,
                                            lnxw+(size_t)l*768, lnxb+(size_t)l*768, gnh16);
    BGEMM(BEPI_RES_GM, gnh16, do_, xs, nullptr, adal+1536, nullptr, 55296, 8192,768,768);
    // --- chanmix ---
    ln_shift_cm_k<<<dim3(8192),dim3(256),0,stream>>>(
        xs, ln2w+(size_t)l*768, ln2b+(size_t)l*768, adal, fmaa+(size_t)l*1536, xk16, xr16);
    {
      BGrp5 G;
      G.g[0].A=xk16; G.g[0].B=dfk; G.g[0].C=kbig16; G.g[0].epi=3; G.g[0].N=2688; G.g[0].gx=21;
      G.g[1].A=xr16; G.g[1].B=dfr; G.g[1].C=gb16;   G.g[1].epi=7; G.g[1].N=768;  G.g[1].gx=6;
      G.g[2]=G.g[1]; G.g[3]=G.g[1]; G.g[4]=G.g[1];
      bgemm_grp_k<<<dim3(21,64,2),dim3(256),0,stream>>>(G, 8192, 768);
    }
    BGEMM(BEPI_RES_GP16, kbig16, dfv, xs, nullptr, adal+3840, gb16, 55296, 8192,768,2688);
  }

  // ---- final layer ----
  ln_mod_k<<<dim3(8192),dim3(256),0,stream>>>(xs, hmodf, nullptr, nullptr, fla, 1536, 0, 768, 1e-6f);
  GEMM(EPI_NONE,true, hmodf, flw, pout, flb, 8192,16,768);
  unpatch_k<<<dim3(512),dim3(256),0,stream>>>(pout, (float*)d_out);
}

// Round 9
// 8544.863 us; speedup vs baseline: 1.0711x; 1.0711x over previous
//
#include <hip/hip_runtime.h>
#include <math.h>

// ---------------------------------------------------------------------------
// DiT-RWKV forward. bf16-MFMA everywhere + chunked MFMA WKV.
// Round 9: exact r7 structure (separate td1 + wd GEMMs, r7 wkv w/ prefetched
// wd). Single isolated change vs r7: tm_w2 consumed as bf16 in five_mix.
// B=32, T=256, C=768, H=12, N=64, FF=2688, L=12, HC=384, IMG=32, P=2
// ---------------------------------------------------------------------------

typedef short  s16x8 __attribute__((ext_vector_type(8)));
typedef float  f32x4 __attribute__((ext_vector_type(4)));
typedef __attribute__((address_space(1))) const void as1_cv;
typedef __attribute__((address_space(3))) void as3_v;

#define GLDS16(gp, lp) __builtin_amdgcn_global_load_lds( \
    (as1_cv*)(unsigned long long)(const void*)(gp), \
    (as3_v*)(unsigned int)(unsigned long long)(void*)(lp), 16, 0, 0)

static __device__ __forceinline__ float sigf(float x){ return 1.f/(1.f+expf(-x)); }
static __device__ __forceinline__ unsigned short f2b(float x){
  unsigned int u = __builtin_bit_cast(unsigned int, x);
  unsigned int r = (u + 0x7FFFu + ((u >> 16) & 1u)) >> 16;
  return (unsigned short)r;
}
static __device__ __forceinline__ float b2f(unsigned short h){
  unsigned int u = ((unsigned int)h)<<16; return __builtin_bit_cast(float,u);
}

// ---------------- workspace layout (float offsets) ----------------
static const size_t O_XS    = 0ull;
static const size_t O_HMOD  = 6291456ull;    // hmod16 (bf16)
static const size_t O_ADA   = 12582912ull;
static const size_t O_FLA   = 14352384ull;
static const size_t O_T2    = 14401536ull;
static const size_t O_SC    = 14426112ull;
static const size_t O_TI    = 14450688ull;
static const size_t O_T1    = 14458880ull;
static const size_t O_ST1   = 14483456ull;
static const size_t O_ST2   = 14485504ull;
static const size_t O_XEW16 = 14487552ull;
static const size_t O_WL16  = 15077376ull;   // 4067328 f (8134656 bf16)
static const size_t O_BIG   = 19144704ull;
// layer-phase members (offsets within BIG):
static const size_t L_XW    = 0ull;
static const size_t L_XX    = 6291456ull;    // xx16
static const size_t L_XXX   = 12582912ull;   // xxx16 then rb16
static const size_t L_KB    = 18874368ull;
static const size_t L_VB    = 25165824ull;
static const size_t L_GB    = 31457280ull;   // gb16
static const size_t L_WD    = 37748736ull;   // wd fp32
static const size_t L_MIXB  = 50331648ull;
static const size_t L_WT    = 51642368ull;   // wt16: 8192 x 64 bf16
static const size_t L_XK16  = 52166656ull;
static const size_t L_XV16  = 55312384ull;
static const size_t L_XR16  = 58458112ull;
static const size_t L_XG16  = 61603840ull;
static const size_t L_GNH16 = 64749568ull;
static const size_t L_KBIG16= 67895296ull;
// stem-phase members (alias onto BIG):
static const size_t S_IMG1  = 0ull;
static const size_t S_IMG2  = 12582912ull;
static const size_t S_PAD16 = 25165824ull;
static const size_t S_WTAP16= 33128448ull;
static const size_t S_PM16  = 34971648ull;

// ---------------- fp32 GEMM (small/odd shapes) ----------------
enum { EPI_NONE=0, EPI_SILU=1 };

template<int EPI, bool TB>
__global__ __launch_bounds__(256) void gemm_k(
    const float* __restrict__ A, const float* __restrict__ B,
    float* __restrict__ C, const float* __restrict__ bias,
    int M, int N, int K)
{
  __shared__ __align__(16) float As[16][68];
  __shared__ __align__(16) float Bs[16][68];
  const int tid = threadIdx.x;
  const int tx = tid & 15, ty = tid >> 4;
  const int row0 = blockIdx.y * 64, col0 = blockIdx.x * 64;
  const int lr = tid >> 2;
  const int lk = (tid & 3) << 2;
  float acc[4][4] = {};
  for (int k0 = 0; k0 < K; k0 += 16) {
    {
      int gr = row0 + lr;
      float4 v = make_float4(0.f,0.f,0.f,0.f);
      if (gr < M) v = *reinterpret_cast<const float4*>(A + (size_t)gr*K + (k0 + lk));
      As[lk+0][lr]=v.x; As[lk+1][lr]=v.y; As[lk+2][lr]=v.z; As[lk+3][lr]=v.w;
    }
    if (TB) {
      int gr = col0 + lr;
      float4 v = make_float4(0.f,0.f,0.f,0.f);
      if (gr < N) v = *reinterpret_cast<const float4*>(B + (size_t)gr*K + (k0 + lk));
      Bs[lk+0][lr]=v.x; Bs[lk+1][lr]=v.y; Bs[lk+2][lr]=v.z; Bs[lk+3][lr]=v.w;
    } else {
      int kr = tid >> 4;
      int gc = col0 + ((tid & 15) << 2);
      float4 v = make_float4(0.f,0.f,0.f,0.f);
      if (gc < N) v = *reinterpret_cast<const float4*>(B + (size_t)(k0+kr)*N + gc);
      Bs[kr][((tid&15)<<2)+0]=v.x; Bs[kr][((tid&15)<<2)+1]=v.y;
      Bs[kr][((tid&15)<<2)+2]=v.z; Bs[kr][((tid&15)<<2)+3]=v.w;
    }
    __syncthreads();
    #pragma unroll
    for (int kk=0;kk<16;kk++){
      const float4 a4 = *reinterpret_cast<const float4*>(&As[kk][ty<<2]);
      const float4 b4 = *reinterpret_cast<const float4*>(&Bs[kk][tx<<2]);
      const float av[4]={a4.x,a4.y,a4.z,a4.w};
      const float bv[4]={b4.x,b4.y,b4.z,b4.w};
      #pragma unroll
      for (int i=0;i<4;i++)
        #pragma unroll
        for (int j=0;j<4;j++)
          acc[i][j]=fmaf(av[i],bv[j],acc[i][j]);
    }
    __syncthreads();
  }
  #pragma unroll
  for (int i=0;i<4;i++){
    const int r = row0 + (ty<<2) + i;
    if (r >= M) break;
    #pragma unroll
    for (int j=0;j<4;j++){
      const int c = col0 + (tx<<2) + j;
      if (c >= N) break;
      float v = acc[i][j];
      if (bias) v += bias[c];
      const size_t idx = (size_t)r*N + c;
      if (EPI==EPI_NONE)        C[idx]=v;
      else if (EPI==EPI_SILU)   C[idx]=v*sigf(v);
    }
  }
}

#define GEMM(EPI,TB,A,B,C,bias,M,N,K) \
  gemm_k<EPI,TB><<<dim3(((N)+63)/64,((M)+63)/64),dim3(256),0,stream>>>((A),(B),(C),(bias),(M),(N),(K))

// ---------------- bf16 MFMA GEMM: 128x128 tile, BK=64 ----------------------
enum { BEPI_F32=0, BEPI_BIAS_F32, BEPI_SILU_F32, BEPI_SIG_F32, BEPI_RELU2_BF16,
       BEPI_RES_GM, BEPI_RES_GP16, BEPI_TANH_BF16, BEPI_WDEC_F32 };

template<int EPI>
__global__ __launch_bounds__(256) void bgemm_k(
    const unsigned short* __restrict__ A, const unsigned short* __restrict__ B,
    void* __restrict__ Cv, const float* __restrict__ bias,
    const float* __restrict__ p1, const void* __restrict__ p2, int pstride,
    int M, int N, int K)
{
  __shared__ __align__(16) unsigned short As[128][64];
  __shared__ __align__(16) unsigned short Bs[128][64];
  const int tid = threadIdx.x;
  const int w = tid >> 6, lane = tid & 63;
  const int row0 = blockIdx.y * 128, col0 = blockIdx.x * 128;
  const int wr = w >> 1, wc = w & 1;
  const int l15 = lane & 15, l4 = lane >> 4;
  const int kkc = ((lane & 7) ^ (lane >> 3)) * 8;
  f32x4 acc[4][4] = {};
  for (int k0 = 0; k0 < K; k0 += 64) {
    #pragma unroll
    for (int i = 0; i < 4; i++) {
      const int rb = i*32 + w*8;
      const int r  = rb + (lane >> 3);
      GLDS16(A + (size_t)(row0 + r)*K + k0 + kkc, &As[rb][0]);
      GLDS16(B + (size_t)(col0 + r)*K + k0 + kkc, &Bs[rb][0]);
    }
    __syncthreads();
    #pragma unroll
    for (int ks = 0; ks < 2; ks++) {
      s16x8 af[4], bf[4];
      #pragma unroll
      for (int m = 0; m < 4; m++) {
        const int r = wr*64 + m*16 + l15;
        const int sl = (ks*4 + l4) ^ (r & 7);
        af[m] = *reinterpret_cast<const s16x8*>(&As[r][sl*8]);
      }
      #pragma unroll
      for (int n = 0; n < 4; n++) {
        const int r = wc*64 + n*16 + l15;
        const int sl = (ks*4 + l4) ^ (r & 7);
        bf[n] = *reinterpret_cast<const s16x8*>(&Bs[r][sl*8]);
      }
      #pragma unroll
      for (int m = 0; m < 4; m++)
        #pragma unroll
        for (int n = 0; n < 4; n++)
          acc[m][n] = __builtin_amdgcn_mfma_f32_16x16x32_bf16(af[m], bf[n], acc[m][n], 0, 0, 0);
    }
    __syncthreads();
  }
  float* Cf = (float*)Cv; unsigned short* Ch = (unsigned short*)Cv;
  const unsigned short* p2h = (const unsigned short*)p2;
  #pragma unroll
  for (int m = 0; m < 4; m++) {
    const int rbase = row0 + wr*64 + m*16 + (l4<<2);
    #pragma unroll
    for (int n = 0; n < 4; n++) {
      const int c = col0 + wc*64 + n*16 + l15;
      if (c >= N) continue;
      #pragma unroll
      for (int q = 0; q < 4; q++) {
        const int r = rbase + q;
        const int bb = r >> 8;
        float v = acc[m][n][q];
        const size_t idx = (size_t)r*N + c;
        if (EPI==BEPI_F32)            Cf[idx] = v;
        else if (EPI==BEPI_BIAS_F32)  Cf[idx] = v + bias[c];
        else if (EPI==BEPI_SILU_F32)  Cf[idx] = v*sigf(v);
        else if (EPI==BEPI_SIG_F32)   Cf[idx] = sigf(v);
        else if (EPI==BEPI_RELU2_BF16){ float t=fmaxf(v,0.f); Ch[idx] = f2b(t*t); }
        else if (EPI==BEPI_RES_GM)    Cf[idx] += p1[(size_t)bb*pstride + c]*v;
        else if (EPI==BEPI_RES_GP16)  Cf[idx] += p1[(size_t)bb*pstride + c]*(b2f(p2h[idx])*v);
        else if (EPI==BEPI_TANH_BF16) Ch[idx] = f2b(tanhf(v));
        else if (EPI==BEPI_WDEC_F32)  Cf[idx] = expf(-expf(v + p1[c]));
      }
    }
  }
}

#define BGEMM(EPI,A16,B16,Cp,bias,p1,p2,ps,M,N,K) \
  bgemm_k<EPI><<<dim3(((N)+127)/128,(M)/128),dim3(256),0,stream>>>( \
    (const unsigned short*)(A16),(const unsigned short*)(B16),(void*)(Cp),(bias),(p1),(p2),(ps),(M),(N),(K))

// ---------------- grouped bf16 GEMM (z = group id) ----------------
// epi: 0 f32, 1 silu f32, 3 relu2 bf16, 4 bf16, 5 silu bf16, 7 sig bf16
struct BGrp { const unsigned short* A; const unsigned short* B; void* C;
              int epi; int N; int gx; };
struct BGrp4 { BGrp g[4]; };

__global__ __launch_bounds__(256) void bgemm_grp_k(BGrp4 G, int M, int K)
{
  const BGrp gr = G.g[blockIdx.z];
  if ((int)blockIdx.x >= gr.gx) return;
  __shared__ __align__(16) unsigned short As[128][64];
  __shared__ __align__(16) unsigned short Bs[128][64];
  const int tid = threadIdx.x;
  const int w = tid >> 6, lane = tid & 63;
  const int row0 = blockIdx.y * 128, col0 = blockIdx.x * 128;
  const int wr = w >> 1, wc = w & 1;
  const int l15 = lane & 15, l4 = lane >> 4;
  const int kkc = ((lane & 7) ^ (lane >> 3)) * 8;
  const int N = gr.N;
  f32x4 acc[4][4] = {};
  for (int k0 = 0; k0 < K; k0 += 64) {
    #pragma unroll
    for (int i = 0; i < 4; i++) {
      const int rb = i*32 + w*8;
      const int r  = rb + (lane >> 3);
      GLDS16(gr.A + (size_t)(row0 + r)*K + k0 + kkc, &As[rb][0]);
      GLDS16(gr.B + (size_t)(col0 + r)*K + k0 + kkc, &Bs[rb][0]);
    }
    __syncthreads();
    #pragma unroll
    for (int ks = 0; ks < 2; ks++) {
      s16x8 af[4], bf[4];
      #pragma unroll
      for (int m = 0; m < 4; m++) {
        const int r = wr*64 + m*16 + l15;
        const int sl = (ks*4 + l4) ^ (r & 7);
        af[m] = *reinterpret_cast<const s16x8*>(&As[r][sl*8]);
      }
      #pragma unroll
      for (int n = 0; n < 4; n++) {
        const int r = wc*64 + n*16 + l15;
        const int sl = (ks*4 + l4) ^ (r & 7);
        bf[n] = *reinterpret_cast<const s16x8*>(&Bs[r][sl*8]);
      }
      #pragma unroll
      for (int m = 0; m < 4; m++)
        #pragma unroll
        for (int n = 0; n < 4; n++)
          acc[m][n] = __builtin_amdgcn_mfma_f32_16x16x32_bf16(af[m], bf[n], acc[m][n], 0, 0, 0);
    }
    __syncthreads();
  }
  float* Cf = (float*)gr.C; unsigned short* Ch = (unsigned short*)gr.C;
  #pragma unroll
  for (int m = 0; m < 4; m++) {
    const int rbase = row0 + wr*64 + m*16 + (l4<<2);
    #pragma unroll
    for (int n = 0; n < 4; n++) {
      const int c = col0 + wc*64 + n*16 + l15;
      #pragma unroll
      for (int q = 0; q < 4; q++) {
        const int r = rbase + q;
        float v = acc[m][n][q];
        const size_t idx = (size_t)r*N + c;
        switch (gr.epi) {
          case 0: Cf[idx] = v; break;
          case 1: Cf[idx] = v*sigf(v); break;
          case 3: { float t=fmaxf(v,0.f); Ch[idx] = f2b(t*t); } break;
          case 4: Ch[idx] = f2b(v); break;
          case 5: Ch[idx] = f2b(v*sigf(v)); break;
          default: Ch[idx] = f2b(sigf(v)); break;
        }
      }
    }
  }
}

// ---------------- conv stem ----------------
__global__ __launch_bounds__(256) void conv1_k(
    const float* __restrict__ x, const float* __restrict__ w,
    const float* __restrict__ bias, float* __restrict__ out)
{
  const int blk = blockIdx.x; const int bb = blk / 384; const int oc = blk % 384;
  __shared__ __align__(16) float sIn[4*1296];
  __shared__ __align__(16) float sW[100];
  const int tid = threadIdx.x;
  for (int idx=tid; idx<4*1296; idx+=256){
    int ic = idx/1296; int rem = idx - ic*1296;
    int yy = rem/36, xx = rem - yy*36;
    int gy = yy-2, gx = xx-2;
    float v = 0.f;
    if ((unsigned)gy < 32u && (unsigned)gx < 32u)
      v = x[(((size_t)bb*4+ic)*32+gy)*32+gx];
    sIn[idx]=v;
  }
  if (tid < 100) sW[tid] = w[(size_t)oc*100 + tid];
  __syncthreads();
  const float bv = bias[oc];
  #pragma unroll
  for (int i=0;i<4;i++){
    int p = tid + 256*i; int py=p>>5, px=p&31;
    int pb = py*36+px;
    float acc = bv;
    #pragma unroll
    for (int ic=0;ic<4;ic++)
      #pragma unroll
      for (int ky=0;ky<5;ky++)
        #pragma unroll
        for (int kx=0;kx<5;kx++)
          acc = fmaf(sIn[ic*1296 + pb + ky*36+kx], sW[ic*25+ky*5+kx], acc);
    out[((size_t)(bb*384+oc))*1024 + p] = acc*sigf(acc);
  }
}

__global__ __launch_bounds__(256) void gn_stats_nchw_k(
    const float* __restrict__ h, float* __restrict__ stats)
{
  const int blk = blockIdx.x;
  const size_t base = (size_t)blk*12288;
  const int tid = threadIdx.x;
  float s=0.f, s2=0.f;
  for (int idx=tid; idx<12288; idx+=256){ float v=h[base+idx]; s+=v; s2=fmaf(v,v,s2); }
  #pragma unroll
  for (int mask=32; mask>=1; mask>>=1){ s += __shfl_xor(s,mask); s2 += __shfl_xor(s2,mask); }
  __shared__ float ps[8];
  if ((tid&63)==0){ ps[tid>>6]=s; ps[4+(tid>>6)]=s2; }
  __syncthreads();
  if (tid==0){
    s = ps[0]+ps[1]+ps[2]+ps[3]; s2 = ps[4]+ps[5]+ps[6]+ps[7];
    float mean = s*(1.f/12288.f);
    float var  = s2*(1.f/12288.f) - mean*mean;
    stats[blk*2] = mean; stats[blk*2+1] = rsqrtf(var + 1e-5f);
  }
}

__global__ void zero16_k(unsigned short* __restrict__ p)
{
  size_t i = ((size_t)blockIdx.x*256 + threadIdx.x)*8;
  *reinterpret_cast<uint4*>(p + i) = make_uint4(0u,0u,0u,0u);
}

__global__ __launch_bounds__(256) void pad_apply_k(
    const float* __restrict__ img1, const float* __restrict__ stats,
    const float* __restrict__ w, const float* __restrict__ bgn,
    unsigned short* __restrict__ pad)
{
  __shared__ float t[8][33];
  const int b = blockIdx.x >> 5, y = blockIdx.x & 31;
  const int tid = threadIdx.x;
  for (int ic0 = 0; ic0 < 384; ic0 += 8) {
    const int icr = tid >> 5, xr = tid & 31;
    t[icr][xr] = img1[(((size_t)b*384 + ic0+icr)*32 + y)*32 + xr];
    __syncthreads();
    const int xw_ = tid >> 3, icw = tid & 7;
    const int ch = ic0 + icw;
    const int g = ch / 12;
    const float mean = stats[(b*32+g)*2], rstd = stats[(b*32+g)*2+1];
    float v = (t[icw][xw_] - mean)*rstd*w[ch] + bgn[ch];
    pad[(((size_t)b*36 + y+2)*36 + (xw_+2))*384 + ch] = f2b(v);
    __syncthreads();
  }
}

__global__ __launch_bounds__(256) void wrepack_k(
    const float* __restrict__ w, unsigned short* __restrict__ wtap)
{
  __shared__ float t[9600];
  const int oc = blockIdx.x; const int tid = threadIdx.x;
  for (int i=tid;i<9600;i+=256) t[i] = w[(size_t)oc*9600 + i];
  __syncthreads();
  for (int i=tid;i<9600;i+=256){
    int tap=i/384, ic=i-tap*384;
    wtap[((size_t)tap*384 + oc)*384 + ic] = f2b(t[ic*25+tap]);
  }
}

// conv2 implicit-GEMM, ic-outer / tap-inner, bf16 out, XCD-chunk swizzle
__global__ __launch_bounds__(256) void conv2m_k(
    const unsigned short* __restrict__ inp,
    const unsigned short* __restrict__ wtap,
    const float* __restrict__ bias, unsigned short* __restrict__ out)
{
  __shared__ __align__(16) unsigned short As[128][64];
  __shared__ __align__(16) unsigned short Bs[128][64];
  const int s = (blockIdx.x % 8) * 96 + blockIdx.x / 8;
  const int ot = s / 256; const int rem = s % 256;
  const int b = rem >> 3, pt = rem & 7;
  const int y0 = pt * 4, oc0 = ot * 128;
  const int tid = threadIdx.x, w = tid>>6, lane = tid&63;
  const int wr = w>>1, wc = w&1;
  const int l15 = lane & 15, l4 = lane >> 4;
  const int kkc = ((lane&7) ^ (lane>>3)) * 8;
  f32x4 acc[4][4] = {};
  for (int ic0 = 0; ic0 < 384; ic0 += 64) {
    for (int dy = 0; dy < 5; dy++) {
      for (int dx = 0; dx < 5; dx++) {
        const int tap = dy*5 + dx;
        #pragma unroll
        for (int i = 0; i < 4; i++) {
          const int rb = i*32 + w*8;
          const int r = rb + (lane>>3);
          const int py = r >> 5, px = r & 31;
          GLDS16(inp + (((size_t)(b*36 + y0+py+dy))*36 + (px+dx))*384 + ic0 + kkc, &As[rb][0]);
          GLDS16(wtap + ((size_t)tap*384 + oc0 + r)*384 + ic0 + kkc, &Bs[rb][0]);
        }
        __syncthreads();
        #pragma unroll
        for (int ks = 0; ks < 2; ks++) {
          s16x8 af[4], bf[4];
          #pragma unroll
          for (int m = 0; m < 4; m++) {
            const int r = wr*64 + m*16 + l15;
            const int sl = (ks*4 + l4) ^ (r & 7);
            af[m] = *reinterpret_cast<const s16x8*>(&As[r][sl*8]);
          }
          #pragma unroll
          for (int n = 0; n < 4; n++) {
            const int r = wc*64 + n*16 + l15;
            const int sl = (ks*4 + l4) ^ (r & 7);
            bf[n] = *reinterpret_cast<const s16x8*>(&Bs[r][sl*8]);
          }
          #pragma unroll
          for (int m = 0; m < 4; m++)
            #pragma unroll
            for (int n = 0; n < 4; n++)
              acc[m][n] = __builtin_amdgcn_mfma_f32_16x16x32_bf16(af[m], bf[n], acc[m][n], 0, 0, 0);
        }
        __syncthreads();
      }
    }
  }
  #pragma unroll
  for (int m = 0; m < 4; m++) {
    #pragma unroll
    for (int n = 0; n < 4; n++) {
      const int oc = oc0 + wc*64 + n*16 + l15;
      const float bv = bias[oc];
      #pragma unroll
      for (int q = 0; q < 4; q++) {
        const int p = wr*64 + m*16 + (l4<<2) + q;
        const int py = p >> 5, px = p & 31;
        float v = acc[m][n][q] + bv;
        out[((size_t)b*1024 + (y0+py)*32 + px)*384 + oc] = f2b(v*sigf(v));
      }
    }
  }
}

__global__ __launch_bounds__(256) void gn_stats_nhwc_k(
    const unsigned short* __restrict__ h, float* __restrict__ stats)
{
  const int b = blockIdx.x >> 5, g = blockIdx.x & 31;
  const int tid = threadIdx.x;
  float s=0.f, s2=0.f;
  for (int idx=tid; idx<12288; idx+=256){
    int p = idx/12, c = idx - p*12;
    float v = b2f(h[((size_t)b*1024+p)*384 + g*12 + c]);
    s+=v; s2=fmaf(v,v,s2);
  }
  #pragma unroll
  for (int mask=32; mask>=1; mask>>=1){ s += __shfl_xor(s,mask); s2 += __shfl_xor(s2,mask); }
  __shared__ float ps[8];
  if ((tid&63)==0){ ps[tid>>6]=s; ps[4+(tid>>6)]=s2; }
  __syncthreads();
  if (tid==0){
    s = ps[0]+ps[1]+ps[2]+ps[3]; s2 = ps[4]+ps[5]+ps[6]+ps[7];
    float mean = s*(1.f/12288.f);
    float var  = s2*(1.f/12288.f) - mean*mean;
    stats[(b*32+g)*2] = mean; stats[(b*32+g)*2+1] = rsqrtf(var + 1e-5f);
  }
}

__global__ void patchify_gn_k(const unsigned short* __restrict__ h, const float* __restrict__ stats,
                              const float* __restrict__ w, const float* __restrict__ bgn,
                              unsigned short* __restrict__ pm)
{
  int idx = blockIdx.x*256 + threadIdx.x;
  int row = idx/1536, f = idx - row*1536;
  int c = f>>2; int p=(f>>1)&1; int q=f&1;
  int bb=row>>8; int tok=row&255; int gh=tok>>4, gw=tok&15;
  int pix = (gh*2+p)*32 + gw*2+q;
  int g = c / 12;
  float mean = stats[(bb*32+g)*2], rstd = stats[(bb*32+g)*2+1];
  float v = (b2f(h[((size_t)bb*1024 + pix)*384 + c]) - mean)*rstd*w[c] + bgn[c];
  pm[idx] = f2b(v);
}

// ---------------- conditioning / misc ----------------
__global__ void temb_in_k(const float* __restrict__ t, float* __restrict__ out)
{
  int bb = blockIdx.x; int i = threadIdx.x;
  float fr = expf(-logf(10000.f) * (float)i / 128.f);
  float ang = t[bb]*fr;
  out[bb*256+i]     = cosf(ang);
  out[bb*256+128+i] = sinf(ang);
}

__global__ void siluc_k(const float* __restrict__ t2, const float* __restrict__ ytab,
                        const int* __restrict__ y, float* __restrict__ sc)
{
  int bb = blockIdx.x; int tid = threadIdx.x;
  int cls = y[bb];
  for (int c=tid; c<768; c+=256){
    float v = t2[bb*768+c] + ytab[(size_t)cls*768+c];
    sc[bb*768+c] = v*sigf(v);
  }
}

__global__ __launch_bounds__(256) void ln_mod_k(
    const float* __restrict__ in, float* __restrict__ out,
    const float* __restrict__ w, const float* __restrict__ b,
    const float* __restrict__ mod, int mstride, int sh_off, int sc_off, float eps)
{
  const int m = blockIdx.x; const int tid = threadIdx.x;
  const size_t base = (size_t)m*768;
  float v0=in[base+tid], v1=in[base+tid+256], v2=in[base+tid+512];
  float s = v0+v1+v2;
  float s2 = fmaf(v0,v0,fmaf(v1,v1,v2*v2));
  #pragma unroll
  for (int mask=32; mask>=1; mask>>=1){ s += __shfl_xor(s,mask); s2 += __shfl_xor(s2,mask); }
  __shared__ float ps[8];
  if ((tid&63)==0){ ps[tid>>6]=s; ps[4+(tid>>6)]=s2; }
  __syncthreads();
  s = ps[0]+ps[1]+ps[2]+ps[3]; s2 = ps[4]+ps[5]+ps[6]+ps[7];
  const float mean = s*(1.f/768.f);
  const float var  = s2*(1.f/768.f) - mean*mean;
  const float rstd = rsqrtf(var + eps);
  const int bb = m >> 8;
  #pragma unroll
  for (int k=0;k<3;k++){
    const int c = tid + k*256;
    float v = (k==0)?v0:((k==1)?v1:v2);
    float xh = (v-mean)*rstd;
    if (w) xh = fmaf(xh, w[c], b[c]);
    if (mod){
      float scv = mod[(size_t)bb*mstride + sc_off + c];
      float shv = mod[(size_t)bb*mstride + sh_off + c];
      xh = fmaf(xh, 1.f+scv, shv);
    }
    out[base+c] = xh;
  }
}

// fused LN+mod+token-shift (timemix); hmod/xx bf16
__global__ __launch_bounds__(256) void ln_shift_tm_k(
    const float* __restrict__ xs, const float* __restrict__ w, const float* __restrict__ b,
    const float* __restrict__ mod, const float* __restrict__ maa0,
    unsigned short* __restrict__ hmod16, unsigned short* __restrict__ xx16,
    unsigned short* __restrict__ xxx16)
{
  const int m = blockIdx.x, tid = threadIdx.x;
  const size_t base = (size_t)m*768;
  const int t = m & 255, bb = m >> 8;
  float c0=xs[base+tid], c1=xs[base+tid+256], c2=xs[base+tid+512];
  float p0=0.f,p1=0.f,p2=0.f;
  if (t) { p0=xs[base-768+tid]; p1=xs[base-512+tid]; p2=xs[base-256+tid]; }
  float sc_=c0+c1+c2, sc2=fmaf(c0,c0,fmaf(c1,c1,c2*c2));
  float sp_=p0+p1+p2, sp2=fmaf(p0,p0,fmaf(p1,p1,p2*p2));
  #pragma unroll
  for (int mask=32; mask>=1; mask>>=1){
    sc_+=__shfl_xor(sc_,mask); sc2+=__shfl_xor(sc2,mask);
    sp_+=__shfl_xor(sp_,mask); sp2+=__shfl_xor(sp2,mask);
  }
  __shared__ float ps[16];
  if ((tid&63)==0){ int wv=tid>>6; ps[wv]=sc_; ps[4+wv]=sc2; ps[8+wv]=sp_; ps[12+wv]=sp2; }
  __syncthreads();
  sc_=ps[0]+ps[1]+ps[2]+ps[3]; sc2=ps[4]+ps[5]+ps[6]+ps[7];
  sp_=ps[8]+ps[9]+ps[10]+ps[11]; sp2=ps[12]+ps[13]+ps[14]+ps[15];
  const float mc = sc_*(1.f/768.f), rc = rsqrtf(sc2*(1.f/768.f)-mc*mc + 1e-5f);
  const float mp = sp_*(1.f/768.f), rp = rsqrtf(sp2*(1.f/768.f)-mp*mp + 1e-5f);
  #pragma unroll
  for (int k=0;k<3;k++){
    const int c = tid + k*256;
    const float scv = mod[(size_t)bb*55296 + 768 + c];
    const float shv = mod[(size_t)bb*55296 + c];
    float cv = (k==0)?c0:((k==1)?c1:c2);
    float h = fmaf((cv-mc)*rc, w[c], b[c]);
    h = fmaf(h, 1.f+scv, shv);
    float pv = 0.f;
    if (t) {
      float pk = (k==0)?p0:((k==1)?p1:p2);
      pv = fmaf((pk-mp)*rp, w[c], b[c]);
      pv = fmaf(pv, 1.f+scv, shv);
    }
    const float d = pv - h;
    hmod16[base+c] = f2b(h);
    xx16[base+c] = f2b(d);
    xxx16[base+c] = f2b(fmaf(d, maa0[c], h));
  }
}

// fused LN+mod+token-shift (chanmix)
__global__ __launch_bounds__(256) void ln_shift_cm_k(
    const float* __restrict__ xs, const float* __restrict__ w, const float* __restrict__ b,
    const float* __restrict__ mod, const float* __restrict__ fmaa,
    unsigned short* __restrict__ xk16, unsigned short* __restrict__ xr16)
{
  const int m = blockIdx.x, tid = threadIdx.x;
  const size_t base = (size_t)m*768;
  const int t = m & 255, bb = m >> 8;
  float c0=xs[base+tid], c1=xs[base+tid+256], c2=xs[base+tid+512];
  float p0=0.f,p1=0.f,p2=0.f;
  if (t) { p0=xs[base-768+tid]; p1=xs[base-512+tid]; p2=xs[base-256+tid]; }
  float sc_=c0+c1+c2, sc2=fmaf(c0,c0,fmaf(c1,c1,c2*c2));
  float sp_=p0+p1+p2, sp2=fmaf(p0,p0,fmaf(p1,p1,p2*p2));
  #pragma unroll
  for (int mask=32; mask>=1; mask>>=1){
    sc_+=__shfl_xor(sc_,mask); sc2+=__shfl_xor(sc2,mask);
    sp_+=__shfl_xor(sp_,mask); sp2+=__shfl_xor(sp2,mask);
  }
  __shared__ float ps[16];
  if ((tid&63)==0){ int wv=tid>>6; ps[wv]=sc_; ps[4+wv]=sc2; ps[8+wv]=sp_; ps[12+wv]=sp2; }
  __syncthreads();
  sc_=ps[0]+ps[1]+ps[2]+ps[3]; sc2=ps[4]+ps[5]+ps[6]+ps[7];
  sp_=ps[8]+ps[9]+ps[10]+ps[11]; sp2=ps[12]+ps[13]+ps[14]+ps[15];
  const float mc = sc_*(1.f/768.f), rc = rsqrtf(sc2*(1.f/768.f)-mc*mc + 1e-5f);
  const float mp = sp_*(1.f/768.f), rp = rsqrtf(sp2*(1.f/768.f)-mp*mp + 1e-5f);
  #pragma unroll
  for (int k=0;k<3;k++){
    const int c = tid + k*256;
    const float scv = mod[(size_t)bb*55296 + 3072 + c];
    const float shv = mod[(size_t)bb*55296 + 2304 + c];
    float cv = (k==0)?c0:((k==1)?c1:c2);
    float h = fmaf((cv-mc)*rc, w[c], b[c]);
    h = fmaf(h, 1.f+scv, shv);
    float pv = 0.f;
    if (t) {
      float pk = (k==0)?p0:((k==1)?p1:p2);
      pv = fmaf((pk-mp)*rp, w[c], b[c]);
      pv = fmaf(pv, 1.f+scv, shv);
    }
    const float d = pv - h;
    xk16[base+c] = f2b(fmaf(d, fmaa[c], h));
    xr16[base+c] = f2b(fmaf(d, fmaa[768+c], h));
  }
}

// 16 rows/block (512 blocks); tm_w2 read as bf16 (the single r9 change)
__global__ __launch_bounds__(256) void five_mix_k(
    const unsigned short* __restrict__ mix16, const unsigned short* __restrict__ w2,
    const unsigned short* __restrict__ hmod16, const unsigned short* __restrict__ xx16,
    const float* __restrict__ maa15,
    unsigned short* __restrict__ xw, unsigned short* __restrict__ xk,
    unsigned short* __restrict__ xv, unsigned short* __restrict__ xr,
    unsigned short* __restrict__ xg)
{
  __shared__ __align__(16) float smix[16][160];
  const int m0 = blockIdx.x * 16;
  const int tid = threadIdx.x;
  for (int idx=tid; idx<16*160; idx+=256){
    int r = idx/160, d = idx - r*160;
    smix[r][d] = b2f(mix16[(size_t)(m0+r)*160 + d]);
  }
  __syncthreads();
  #pragma unroll 1
  for (int cc=0; cc<3; cc++){
    const int c = tid + cc*256;
    float hv[16], xv_[16];
    #pragma unroll
    for (int r=0;r<16;r++){
      size_t id=(size_t)(m0+r)*768+c;
      hv[r]=b2f(hmod16[id]); xv_[r]=b2f(xx16[id]);
    }
    #pragma unroll 1
    for (int f=0; f<5; f++){
      float acc[16];
      const float base = maa15[f*768 + c];
      #pragma unroll
      for (int r=0;r<16;r++) acc[r]=base;
      #pragma unroll 1
      for (int d4=0; d4<8; d4++){
        float wv[4];
        #pragma unroll
        for (int q=0;q<4;q++) wv[q] = b2f(w2[(size_t)(f*32+d4*4+q)*768 + c]);
        #pragma unroll
        for (int r=0;r<16;r++){
          const float4 mv = *reinterpret_cast<const float4*>(&smix[r][f*32+d4*4]);
          acc[r] = fmaf(mv.x,wv[0],fmaf(mv.y,wv[1],fmaf(mv.z,wv[2],fmaf(mv.w,wv[3],acc[r]))));
        }
      }
      #pragma unroll
      for (int r=0;r<16;r++){
        float val = fmaf(xv_[r], acc[r], hv[r]);
        size_t id = (size_t)(m0+r)*768+c;
        if (f==0) xw[id]=f2b(val);
        else if (f==1) xk[id]=f2b(val);
        else if (f==2) xv[id]=f2b(val);
        else if (f==3) xr[id]=f2b(val);
        else           xg[id]=f2b(val);
      }
    }
  }
}

// ---------------- chunked MFMA WKV (fused head-GN + gate), r7 form ----------
__global__ __launch_bounds__(256) void wkv_k(
    const unsigned short* __restrict__ rg, const unsigned short* __restrict__ kg,
    const unsigned short* __restrict__ vg, const float* __restrict__ wg,
    const unsigned short* __restrict__ gg, const float* __restrict__ u,
    const float* __restrict__ lnxw, const float* __restrict__ lnxb,
    unsigned short* __restrict__ out16)
{
  const int bh = blockIdx.x; const int b = bh/12, h = bh%12;
  const int tid = threadIdx.x;
  const int w = tid >> 6, lane = tid & 63;
  const int l4 = lane >> 4, l15 = lane & 15;
  __shared__ __align__(16) unsigned short r16s[32][64], k16s[32][64], v16s[32][64], g16s[32][64];
  __shared__ __align__(16) float wds[32][64];
  __shared__ __align__(16) float Wl[33][64];
  __shared__ __align__(16) unsigned short rr16[32][64], kk16[32][64];
  __shared__ __align__(16) unsigned short kk2T[64][32], vT[64][32];
  __shared__ __align__(16) unsigned short S16T[64][64];
  __shared__ __align__(16) unsigned short A16[32][32];
  __shared__ float diag[32], ypsum[32][4], ypsq[32][4];

  reinterpret_cast<uint4*>(&S16T[0][0])[tid] = make_uint4(0,0,0,0);
  reinterpret_cast<uint4*>(&S16T[0][0])[256+tid] = make_uint4(0,0,0,0);

  const float u_lane = u[h*64 + lane];
  const int jj = w*16 + l15;
  const float lw = lnxw[h*64 + jj], lb = lnxb[h*64 + jj];
  const size_t gb = (size_t)(b*256)*768 + h*64;

  const int st_t = tid >> 3, st_i = (tid & 7) * 8;
  uint4 pr, pk, pv, pg; float4 pw0, pw1;

#define WKV_LOADC(c_) { \
    const size_t tb = gb + (size_t)((c_)*32 + st_t)*768 + st_i; \
    pr = *reinterpret_cast<const uint4*>(rg + tb); \
    pk = *reinterpret_cast<const uint4*>(kg + tb); \
    pv = *reinterpret_cast<const uint4*>(vg + tb); \
    pg = *reinterpret_cast<const uint4*>(gg + tb); \
    pw0 = *reinterpret_cast<const float4*>(wg + tb); \
    pw1 = *reinterpret_cast<const float4*>(wg + tb + 4); }
#define WKV_STAGE() { \
    *reinterpret_cast<uint4*>(&r16s[st_t][st_i]) = pr; \
    *reinterpret_cast<uint4*>(&k16s[st_t][st_i]) = pk; \
    *reinterpret_cast<uint4*>(&v16s[st_t][st_i]) = pv; \
    *reinterpret_cast<uint4*>(&g16s[st_t][st_i]) = pg; \
    *reinterpret_cast<float4*>(&wds[st_t][st_i]) = pw0; \
    *reinterpret_cast<float4*>(&wds[st_t][st_i+4]) = pw1; }

  f32x4 S_acc[4] = {};

  WKV_LOADC(0);
  WKV_STAGE();
  __syncthreads();

  #pragma unroll 1
  for (int c = 0; c < 8; ++c) {
    if (w == 0) {
      float wv[32];
      #pragma unroll
      for (int t=0;t<32;t++) wv[t] = wds[t][lane];
      float P = 1.f;
      Wl[0][lane] = 1.f;
      #pragma unroll
      for (int t=0;t<32;t++){ P *= wv[t]; Wl[t+1][lane] = P; }
    }
    __syncthreads();
    {
      const int t = st_t, i0 = st_i;
      s16x8 rv = *reinterpret_cast<const s16x8*>(&r16s[t][i0]);
      s16x8 kv = *reinterpret_cast<const s16x8*>(&k16s[t][i0]);
      s16x8 vv = *reinterpret_cast<const s16x8*>(&v16s[t][i0]);
      float4 wa0 = *reinterpret_cast<const float4*>(&Wl[t][i0]);
      float4 wa1 = *reinterpret_cast<const float4*>(&Wl[t][i0+4]);
      float4 wb0 = *reinterpret_cast<const float4*>(&Wl[t+1][i0]);
      float4 wb1 = *reinterpret_cast<const float4*>(&Wl[t+1][i0+4]);
      float4 wf0 = *reinterpret_cast<const float4*>(&Wl[32][i0]);
      float4 wf1 = *reinterpret_cast<const float4*>(&Wl[32][i0+4]);
      float wt_[8] = {wa0.x,wa0.y,wa0.z,wa0.w,wa1.x,wa1.y,wa1.z,wa1.w};
      float wt1[8] = {wb0.x,wb0.y,wb0.z,wb0.w,wb1.x,wb1.y,wb1.z,wb1.w};
      float w32[8] = {wf0.x,wf0.y,wf0.z,wf0.w,wf1.x,wf1.y,wf1.z,wf1.w};
      s16x8 rro, kko;
      #pragma unroll
      for (int e=0;e<8;e++){
        const int i = i0 + e;
        float rf = b2f((unsigned short)rv[e]) * wt_[e];
        float kf = b2f((unsigned short)kv[e]) / wt1[e];
        rro[e] = (short)f2b(rf);
        kko[e] = (short)f2b(kf);
        kk2T[i][(((t>>3)^(i&3))<<3) + (t&7)] = f2b(kf * w32[e]);
        vT[i][(((t>>3)^(i&3))<<3) + (t&7)] = (unsigned short)vv[e];
      }
      const int sc_ = ((i0>>3)^(t&7))<<3;
      *reinterpret_cast<s16x8*>(&rr16[t][sc_]) = rro;
      *reinterpret_cast<s16x8*>(&kk16[t][sc_]) = kko;
      #pragma unroll
      for (int tt=0;tt<8;tt++){
        const int td = w*8 + tt;
        float p = b2f(r16s[td][lane]) * u_lane * b2f(k16s[td][lane]);
        #pragma unroll
        for (int mask=32; mask>=1; mask>>=1) p += __shfl_xor(p, mask);
        if (lane==0) diag[td] = p;
      }
    }
    __syncthreads();
    if (c < 7) WKV_LOADC(c+1);
    f32x4 Y[2] = {};
    s16x8 rrf[2][2];
    #pragma unroll
    for (int m=0;m<2;m++)
      #pragma unroll
      for (int kt=0;kt<2;kt++){
        const int row = m*16 + l15;
        rrf[m][kt] = *reinterpret_cast<const s16x8*>(&rr16[row][(((kt*4+l4)^(row&7))<<3)]);
      }
    #pragma unroll
    for (int m=0;m<2;m++)
      #pragma unroll
      for (int kt=0;kt<2;kt++){
        s16x8 sf = *reinterpret_cast<const s16x8*>(&S16T[jj][(((kt*4+l4)^(jj&7))<<3)]);
        Y[m] = __builtin_amdgcn_mfma_f32_16x16x32_bf16(rrf[m][kt], sf, Y[m], 0,0,0);
      }
    s16x8 vtf = *reinterpret_cast<const s16x8*>(&vT[jj][((l4^(jj&3))<<3)]);
    #pragma unroll
    for (int m=0;m<4;m++){
      const int row = m*16 + l15;
      s16x8 k2f = *reinterpret_cast<const s16x8*>(&kk2T[row][((l4^(row&3))<<3)]);
      #pragma unroll
      for (int q=0;q<4;q++) S_acc[m][q] *= Wl[32][m*16 + l4*4 + q];
      S_acc[m] = __builtin_amdgcn_mfma_f32_16x16x32_bf16(k2f, vtf, S_acc[m], 0,0,0);
    }
    if (w == 0) {
      f32x4 Aac[2][2] = {};
      #pragma unroll
      for (int m=0;m<2;m++)
        #pragma unroll
        for (int n=0;n<2;n++)
          #pragma unroll
          for (int kt=0;kt<2;kt++){
            const int srow = n*16 + l15;
            s16x8 kf = *reinterpret_cast<const s16x8*>(&kk16[srow][(((kt*4+l4)^(srow&7))<<3)]);
            Aac[m][n] = __builtin_amdgcn_mfma_f32_16x16x32_bf16(rrf[m][kt], kf, Aac[m][n], 0,0,0);
          }
      #pragma unroll
      for (int m=0;m<2;m++)
        #pragma unroll
        for (int n=0;n<2;n++)
          #pragma unroll
          for (int q=0;q<4;q++){
            const int t = m*16 + l4*4 + q;
            const int s = n*16 + l15;
            float av = Aac[m][n][q];
            av = (s < t) ? av : ((s == t) ? diag[t] : 0.f);
            A16[t][(((s>>3)^(t&3))<<3) + (s&7)] = f2b(av);
          }
    }
    #pragma unroll
    for (int m=0;m<4;m++)
      #pragma unroll
      for (int q=0;q<4;q++){
        const int i = m*16 + l4*4 + q;
        S16T[jj][(((i>>3)^(jj&7))<<3) + (i&7)] = f2b(S_acc[m][q]);
      }
    __syncthreads();
    #pragma unroll
    for (int m=0;m<2;m++){
      const int row = m*16 + l15;
      s16x8 af = *reinterpret_cast<const s16x8*>(&A16[row][((l4^(row&3))<<3)]);
      Y[m] = __builtin_amdgcn_mfma_f32_16x16x32_bf16(af, vtf, Y[m], 0,0,0);
    }
    #pragma unroll
    for (int m=0;m<2;m++)
      #pragma unroll
      for (int q=0;q<4;q++){
        float s1 = Y[m][q], s2 = s1*s1;
        #pragma unroll
        for (int mask=8; mask>=1; mask>>=1){ s1 += __shfl_xor(s1,mask); s2 += __shfl_xor(s2,mask); }
        if (l15==0){ const int t = m*16 + l4*4 + q; ypsum[t][w]=s1; ypsq[t][w]=s2; }
      }
    __syncthreads();
    #pragma unroll
    for (int m=0;m<2;m++)
      #pragma unroll
      for (int q=0;q<4;q++){
        const int t = m*16 + l4*4 + q;
        float s1 = ypsum[t][0]+ypsum[t][1]+ypsum[t][2]+ypsum[t][3];
        float s2 = ypsq[t][0]+ypsq[t][1]+ypsq[t][2]+ypsq[t][3];
        float mean = s1*(1.f/64.f);
        float var  = s2*(1.f/64.f) - mean*mean;
        float xh = (Y[m][q]-mean)*rsqrtf(var + 6.4e-4f);
        float o = fmaf(xh, lw, lb) * b2f(g16s[t][jj]);
        out16[gb + (size_t)(c*32+t)*768 + jj] = f2b(o);
      }
    if (c < 7) {
      __syncthreads();
      WKV_STAGE();
      __syncthreads();
    }
  }
#undef WKV_LOADC
#undef WKV_STAGE
}

__global__ void unpatch_k(const float* __restrict__ po, float* __restrict__ out)
{
  int idx = blockIdx.x*256 + threadIdx.x;
  int xq=idx&31; int yy=(idx>>5)&31; int ch=(idx>>10)&3; int bb=idx>>12;
  int gh=yy>>1, p=yy&1, gw=xq>>1, q=xq&1;
  out[idx] = po[((size_t)(bb*256+gh*16+gw))*16 + p*8+q*4+ch];
}

// ---------------- fp32 -> bf16 conversions / repacks ----------------
__global__ void f2b_k(const float* __restrict__ s, unsigned short* __restrict__ d)
{
  size_t i = ((size_t)blockIdx.x*256 + threadIdx.x)*8;
  float4 a = *reinterpret_cast<const float4*>(s+i);
  float4 b = *reinterpret_cast<const float4*>(s+i+4);
  s16x8 o;
  o[0]=(short)f2b(a.x); o[1]=(short)f2b(a.y); o[2]=(short)f2b(a.z); o[3]=(short)f2b(a.w);
  o[4]=(short)f2b(b.x); o[5]=(short)f2b(b.y); o[6]=(short)f2b(b.z); o[7]=(short)f2b(b.w);
  *reinterpret_cast<s16x8*>(d + i) = o;
}

// merged per-layer weight convert + mix/decay repack + tm_w2 bf16.
// blocks [0,3744): bulk convert r,k,v,o,g,fr (589824 ea), fk, fv (2064384 ea)
// blocks [3744,5568): tm_w1->(256,768), td_w1->(128,768), td_w2->(768,64), tm_w2 flat
__global__ void f2bw_layer_k(
    const float* __restrict__ r_, const float* __restrict__ k_, const float* __restrict__ v_,
    const float* __restrict__ o_, const float* __restrict__ g_, const float* __restrict__ fr_,
    const float* __restrict__ fk_, const float* __restrict__ fv_,
    const float* __restrict__ tm1, const float* __restrict__ td1, const float* __restrict__ td2,
    const float* __restrict__ tm2, unsigned short* __restrict__ dst)
{
  if (blockIdx.x < 3744) {
    size_t i = ((size_t)blockIdx.x*256 + threadIdx.x)*8;
    const float* s; size_t off;
    if (i < 3538944) {
      unsigned seg = (unsigned)(i / 589824u); off = i - (size_t)seg*589824u;
      s = seg==0?r_:seg==1?k_:seg==2?v_:seg==3?o_:seg==4?g_:fr_;
    } else if (i < 5603328) { s = fk_; off = i - 3538944; }
    else                    { s = fv_; off = i - 5603328; }
    float4 a = *reinterpret_cast<const float4*>(s+off);
    float4 b = *reinterpret_cast<const float4*>(s+off+4);
    s16x8 o;
    o[0]=(short)f2b(a.x); o[1]=(short)f2b(a.y); o[2]=(short)f2b(a.z); o[3]=(short)f2b(a.w);
    o[4]=(short)f2b(b.x); o[5]=(short)f2b(b.y); o[6]=(short)f2b(b.z); o[7]=(short)f2b(b.w);
    *reinterpret_cast<s16x8*>(dst + i) = o;
  } else {
    int idx = (blockIdx.x-3744)*256 + threadIdx.x;   // 0..466943
    unsigned short* rp = dst + 7667712;
    if (idx < 196608) {
      int n = idx/768, k = idx - n*768;
      rp[idx] = (n<160) ? f2b(tm1[(size_t)k*160 + n]) : (unsigned short)0;
    } else if (idx < 294912) {
      int i = idx-196608; int n = i/768, k = i - n*768;
      rp[idx] = (n<64) ? f2b(td1[(size_t)k*64 + n]) : (unsigned short)0;
    } else if (idx < 344064) {
      int i = idx-294912; int n = i/64, k = i - n*64;
      rp[idx] = f2b(td2[(size_t)k*768 + n]);
    } else if (idx < 466944) {
      int i = idx-344064;                    // flat (5,32,768)
      rp[idx] = f2b(tm2[i]);
    }
  }
}

// ---------------------------------------------------------------------------
extern "C" void kernel_launch(void* const* d_in, const int* in_sizes, int n_in,
                              void* d_out, int out_size, void* d_ws, size_t ws_size,
                              hipStream_t stream)
{
  const float* x_in  = (const float*)d_in[0];
  const float* t_in  = (const float*)d_in[1];
  const int*   y_in  = (const int*)  d_in[2];
  const float* c1w   = (const float*)d_in[3];
  const float* c1b   = (const float*)d_in[4];
  const float* gn1w  = (const float*)d_in[5];
  const float* gn1b  = (const float*)d_in[6];
  const float* c2w   = (const float*)d_in[7];
  const float* c2b   = (const float*)d_in[8];
  const float* gn2w  = (const float*)d_in[9];
  const float* gn2b  = (const float*)d_in[10];
  const float* xew   = (const float*)d_in[11];
  const float* xeb   = (const float*)d_in[12];
  const float* tew1  = (const float*)d_in[13];
  const float* teb1  = (const float*)d_in[14];
  const float* tew2  = (const float*)d_in[15];
  const float* teb2  = (const float*)d_in[16];
  const float* ytab  = (const float*)d_in[17];
  const float* ln0w  = (const float*)d_in[18];
  const float* ln0b  = (const float*)d_in[19];
  const float* ln1w  = (const float*)d_in[20];
  const float* ln1b  = (const float*)d_in[21];
  const float* ln2w  = (const float*)d_in[22];
  const float* ln2b  = (const float*)d_in[23];
  const float* amaa  = (const float*)d_in[24];
  const float* tmw1  = (const float*)d_in[25];
  const float* tmw2  = (const float*)d_in[26];
  const float* tdv   = (const float*)d_in[27];
  const float* tdw1  = (const float*)d_in[28];
  const float* tdw2  = (const float*)d_in[29];
  const float* faa   = (const float*)d_in[30];
  const float* rw    = (const float*)d_in[31];
  const float* kw    = (const float*)d_in[32];
  const float* vw    = (const float*)d_in[33];
  const float* ow    = (const float*)d_in[34];
  const float* gw    = (const float*)d_in[35];
  const float* lnxw  = (const float*)d_in[36];
  const float* lnxb  = (const float*)d_in[37];
  const float* fmaa  = (const float*)d_in[38];
  const float* fkw   = (const float*)d_in[39];
  const float* frw   = (const float*)d_in[40];
  const float* fvw   = (const float*)d_in[41];
  const float* adaw  = (const float*)d_in[42];
  const float* adab  = (const float*)d_in[43];
  const float* flaw  = (const float*)d_in[44];
  const float* flab  = (const float*)d_in[45];
  const float* flw   = (const float*)d_in[46];
  const float* flb   = (const float*)d_in[47];

  float* Wf = (float*)d_ws;
  float* xs   = Wf+O_XS;   float* hmodf = Wf+O_HMOD;
  float* ada  = Wf+O_ADA;  float* fla  = Wf+O_FLA;
  float* t2   = Wf+O_T2;   float* sc   = Wf+O_SC;
  float* ti   = Wf+O_TI;   float* t1   = Wf+O_T1;
  float* st1  = Wf+O_ST1;  float* st2  = Wf+O_ST2;
  unsigned short* xew16 = (unsigned short*)(Wf+O_XEW16);
  unsigned short* wl16  = (unsigned short*)(Wf+O_WL16);
  unsigned short* hmod16 = (unsigned short*)(Wf+O_HMOD);
  float* big = Wf+O_BIG;
  float* wd   = big+L_WD;
  unsigned short* xx16  = (unsigned short*)(big+L_XX);
  unsigned short* rb16  = (unsigned short*)(big+L_XXX);
  unsigned short* kb16  = (unsigned short*)(big+L_KB);
  unsigned short* vb16  = (unsigned short*)(big+L_VB);
  unsigned short* gb16  = (unsigned short*)(big+L_GB);
  unsigned short* xw16  = (unsigned short*)(big+L_XW);
  unsigned short* xxx16 = (unsigned short*)(big+L_XXX);
  unsigned short* mixb16= (unsigned short*)(big+L_MIXB);
  unsigned short* wt16  = (unsigned short*)(big+L_WT);
  unsigned short* xk16 = (unsigned short*)(big+L_XK16);
  unsigned short* xv16 = (unsigned short*)(big+L_XV16);
  unsigned short* xr16 = (unsigned short*)(big+L_XR16);
  unsigned short* xg16 = (unsigned short*)(big+L_XG16);
  unsigned short* gnh16 = (unsigned short*)(big+L_GNH16);
  unsigned short* kbig16 = (unsigned short*)(big+L_KBIG16);
  float* img1 = big+S_IMG1;
  unsigned short* img2_16 = (unsigned short*)(big+S_IMG2);
  unsigned short* pad16  = (unsigned short*)(big+S_PAD16);
  unsigned short* wtap16 = (unsigned short*)(big+S_WTAP16);
  unsigned short* pm16   = (unsigned short*)(big+S_PM16);
  float* pout = big+L_MIXB;
  unsigned short* dr  = wl16;
  unsigned short* dk  = wl16 + 589824;
  unsigned short* dv  = wl16 + 1179648;
  unsigned short* do_ = wl16 + 1769472;
  unsigned short* dg  = wl16 + 2359296;
  unsigned short* dfr = wl16 + 2949120;
  unsigned short* dfk = wl16 + 3538944;
  unsigned short* dfv = wl16 + 5603328;
  unsigned short* dtm1t = wl16 + 7667712;
  unsigned short* dtd1t = wl16 + 7864320;
  unsigned short* dtd2t = wl16 + 7962624;   // (768 x 64)
  unsigned short* dtmw2 = wl16 + 8011776;   // (5,32,768) bf16

  // ---- conv stem ----
  conv1_k<<<dim3(32*384),dim3(256),0,stream>>>(x_in, c1w, c1b, img1);
  gn_stats_nchw_k<<<dim3(1024),dim3(256),0,stream>>>(img1, st1);
  zero16_k<<<dim3(7776),dim3(256),0,stream>>>(pad16);
  pad_apply_k<<<dim3(1024),dim3(256),0,stream>>>(img1, st1, gn1w, gn1b, pad16);
  wrepack_k<<<dim3(384),dim3(256),0,stream>>>(c2w, wtap16);
  conv2m_k<<<dim3(768),dim3(256),0,stream>>>(pad16, wtap16, c2b, img2_16);
  gn_stats_nhwc_k<<<dim3(1024),dim3(256),0,stream>>>(img2_16, st2);
  patchify_gn_k<<<dim3(49152),dim3(256),0,stream>>>(img2_16, st2, gn2w, gn2b, pm16);
  f2b_k<<<dim3(576),dim3(256),0,stream>>>(xew, xew16);
  BGEMM(BEPI_BIAS_F32, pm16, xew16, xs, xeb, nullptr,nullptr,0, 8192,768,1536);

  // ---- conditioning ----
  temb_in_k<<<dim3(32),dim3(128),0,stream>>>(t_in, ti);
  GEMM(EPI_SILU,true, ti, tew1, t1, teb1, 32,768,256);
  GEMM(EPI_NONE,true, t1, tew2, t2, teb2, 32,768,768);
  siluc_k<<<dim3(32),dim3(256),0,stream>>>(t2, ytab, y_in, sc);
  GEMM(EPI_NONE,true, sc, adaw, ada, adab, 32,55296,768);
  GEMM(EPI_NONE,true, sc, flaw, fla, flab, 32,1536,768);

  // ---- ln0 ----
  ln_mod_k<<<dim3(8192),dim3(256),0,stream>>>(xs, xs, ln0w, ln0b, nullptr, 0,0,0, 1e-5f);

  for (int l=0; l<12; l++){
    const float* adal = ada + (size_t)l*4608;
    f2bw_layer_k<<<dim3(5568),dim3(256),0,stream>>>(
        rw+(size_t)l*589824, kw+(size_t)l*589824, vw+(size_t)l*589824,
        ow+(size_t)l*589824, gw+(size_t)l*589824, frw+(size_t)l*589824,
        fkw+(size_t)l*2064384, fvw+(size_t)l*2064384,
        tmw1+(size_t)l*122880, tdw1+(size_t)l*49152, tdw2+(size_t)l*49152,
        tmw2+(size_t)l*122880, wl16);
    // --- timemix ---
    ln_shift_tm_k<<<dim3(8192),dim3(256),0,stream>>>(
        xs, ln1w+(size_t)l*768, ln1b+(size_t)l*768, adal, amaa+(size_t)l*4608,
        hmod16, xx16, xxx16);
    BGEMM(BEPI_TANH_BF16, xxx16, dtm1t, mixb16, nullptr,nullptr,nullptr,0, 8192,160,768);
    five_mix_k<<<dim3(512),dim3(256),0,stream>>>(mixb16, dtmw2, hmod16, xx16,
                                                 amaa+(size_t)l*4608+768, xw16,xk16,xv16,xr16,xg16);
    BGEMM(BEPI_TANH_BF16, xw16, dtd1t, wt16, nullptr,nullptr,nullptr,0, 8192,64,768);
    BGEMM(BEPI_WDEC_F32, wt16, dtd2t, wd, nullptr, tdv+(size_t)l*768, nullptr,0, 8192,768,64);
    {
      BGrp4 G;
      G.g[0].A=xr16; G.g[0].B=dr; G.g[0].C=rb16; G.g[0].epi=4; G.g[0].N=768; G.g[0].gx=6;
      G.g[1].A=xk16; G.g[1].B=dk; G.g[1].C=kb16; G.g[1].epi=4; G.g[1].N=768; G.g[1].gx=6;
      G.g[2].A=xv16; G.g[2].B=dv; G.g[2].C=vb16; G.g[2].epi=4; G.g[2].N=768; G.g[2].gx=6;
      G.g[3].A=xg16; G.g[3].B=dg; G.g[3].C=gb16; G.g[3].epi=5; G.g[3].N=768; G.g[3].gx=6;
      bgemm_grp_k<<<dim3(6,64,4),dim3(256),0,stream>>>(G, 8192, 768);
    }
    wkv_k<<<dim3(384),dim3(256),0,stream>>>(rb16, kb16, vb16, wd, gb16, faa+(size_t)l*768,
                                            lnxw+(size_t)l*768, lnxb+(size_t)l*768, gnh16);
    BGEMM(BEPI_RES_GM, gnh16, do_, xs, nullptr, adal+1536, nullptr, 55296, 8192,768,768);
    // --- chanmix ---
    ln_shift_cm_k<<<dim3(8192),dim3(256),0,stream>>>(
        xs, ln2w+(size_t)l*768, ln2b+(size_t)l*768, adal, fmaa+(size_t)l*1536, xk16, xr16);
    {
      BGrp4 G;
      G.g[0].A=xk16; G.g[0].B=dfk; G.g[0].C=kbig16; G.g[0].epi=3; G.g[0].N=2688; G.g[0].gx=21;
      G.g[1].A=xr16; G.g[1].B=dfr; G.g[1].C=gb16;   G.g[1].epi=7; G.g[1].N=768;  G.g[1].gx=6;
      G.g[2]=G.g[1]; G.g[3]=G.g[1];
      bgemm_grp_k<<<dim3(21,64,2),dim3(256),0,stream>>>(G, 8192, 768);
    }
    BGEMM(BEPI_RES_GP16, kbig16, dfv, xs, nullptr, adal+3840, gb16, 55296, 8192,768,2688);
  }

  // ---- final layer ----
  ln_mod_k<<<dim3(8192),dim3(256),0,stream>>>(xs, hmodf, nullptr, nullptr, fla, 1536, 0, 768, 1e-6f);
  GEMM(EPI_NONE,true, hmodf, flw, pout, flb, 8192,16,768);
  unpatch_k<<<dim3(512),dim3(256),0,stream>>>(pout, (float*)d_out);
}

// Round 10
// 8217.748 us; speedup vs baseline: 1.1137x; 1.0398x over previous
//
#include <hip/hip_runtime.h>
#include <math.h>

// ---------------------------------------------------------------------------
// DiT-RWKV forward. bf16-MFMA everywhere + chunked MFMA WKV.
// Round 10: verbatim r7 (best known: 8,238 us) — re-anchor + noise measurement.
// B=32, T=256, C=768, H=12, N=64, FF=2688, L=12, HC=384, IMG=32, P=2
// ---------------------------------------------------------------------------

typedef short  s16x8 __attribute__((ext_vector_type(8)));
typedef float  f32x4 __attribute__((ext_vector_type(4)));
typedef __attribute__((address_space(1))) const void as1_cv;
typedef __attribute__((address_space(3))) void as3_v;

#define GLDS16(gp, lp) __builtin_amdgcn_global_load_lds( \
    (as1_cv*)(unsigned long long)(const void*)(gp), \
    (as3_v*)(unsigned int)(unsigned long long)(void*)(lp), 16, 0, 0)

static __device__ __forceinline__ float sigf(float x){ return 1.f/(1.f+expf(-x)); }
static __device__ __forceinline__ unsigned short f2b(float x){
  unsigned int u = __builtin_bit_cast(unsigned int, x);
  unsigned int r = (u + 0x7FFFu + ((u >> 16) & 1u)) >> 16;
  return (unsigned short)r;
}
static __device__ __forceinline__ float b2f(unsigned short h){
  unsigned int u = ((unsigned int)h)<<16; return __builtin_bit_cast(float,u);
}

// ---------------- workspace layout (float offsets) ----------------
static const size_t O_XS    = 0ull;
static const size_t O_HMOD  = 6291456ull;    // hmod16 (bf16, uses half)
static const size_t O_ADA   = 12582912ull;
static const size_t O_FLA   = 14352384ull;
static const size_t O_T2    = 14401536ull;
static const size_t O_SC    = 14426112ull;
static const size_t O_TI    = 14450688ull;
static const size_t O_T1    = 14458880ull;
static const size_t O_ST1   = 14483456ull;
static const size_t O_ST2   = 14485504ull;
static const size_t O_XEW16 = 14487552ull;
static const size_t O_WL16  = 15077376ull;   // 4030464 f (8060928 bf16)
static const size_t O_BIG   = 19107840ull;
// layer-phase members (offsets within BIG):
static const size_t L_XW    = 0ull;
static const size_t L_XX    = 6291456ull;    // xx16 (bf16)
static const size_t L_XXX   = 12582912ull;   // xxx16 then rb16
static const size_t L_KB    = 18874368ull;
static const size_t L_VB    = 25165824ull;
static const size_t L_GB    = 31457280ull;   // gb16
static const size_t L_WD    = 37748736ull;
static const size_t L_MIXB  = 50331648ull;
static const size_t L_WT    = 51642368ull;
static const size_t L_XK16  = 52166656ull;
static const size_t L_XV16  = 55312384ull;
static const size_t L_XR16  = 58458112ull;
static const size_t L_XG16  = 61603840ull;
static const size_t L_GNH16 = 64749568ull;
static const size_t L_KBIG16= 67895296ull;
// stem-phase members (alias onto BIG):
static const size_t S_IMG1  = 0ull;
static const size_t S_IMG2  = 12582912ull;
static const size_t S_PAD16 = 25165824ull;
static const size_t S_WTAP16= 33128448ull;
static const size_t S_PM16  = 34971648ull;

// ---------------- fp32 GEMM (small/odd shapes) ----------------
enum { EPI_NONE=0, EPI_SILU=1 };

template<int EPI, bool TB>
__global__ __launch_bounds__(256) void gemm_k(
    const float* __restrict__ A, const float* __restrict__ B,
    float* __restrict__ C, const float* __restrict__ bias,
    int M, int N, int K)
{
  __shared__ __align__(16) float As[16][68];
  __shared__ __align__(16) float Bs[16][68];
  const int tid = threadIdx.x;
  const int tx = tid & 15, ty = tid >> 4;
  const int row0 = blockIdx.y * 64, col0 = blockIdx.x * 64;
  const int lr = tid >> 2;
  const int lk = (tid & 3) << 2;
  float acc[4][4] = {};
  for (int k0 = 0; k0 < K; k0 += 16) {
    {
      int gr = row0 + lr;
      float4 v = make_float4(0.f,0.f,0.f,0.f);
      if (gr < M) v = *reinterpret_cast<const float4*>(A + (size_t)gr*K + (k0 + lk));
      As[lk+0][lr]=v.x; As[lk+1][lr]=v.y; As[lk+2][lr]=v.z; As[lk+3][lr]=v.w;
    }
    if (TB) {
      int gr = col0 + lr;
      float4 v = make_float4(0.f,0.f,0.f,0.f);
      if (gr < N) v = *reinterpret_cast<const float4*>(B + (size_t)gr*K + (k0 + lk));
      Bs[lk+0][lr]=v.x; Bs[lk+1][lr]=v.y; Bs[lk+2][lr]=v.z; Bs[lk+3][lr]=v.w;
    } else {
      int kr = tid >> 4;
      int gc = col0 + ((tid & 15) << 2);
      float4 v = make_float4(0.f,0.f,0.f,0.f);
      if (gc < N) v = *reinterpret_cast<const float4*>(B + (size_t)(k0+kr)*N + gc);
      Bs[kr][((tid&15)<<2)+0]=v.x; Bs[kr][((tid&15)<<2)+1]=v.y;
      Bs[kr][((tid&15)<<2)+2]=v.z; Bs[kr][((tid&15)<<2)+3]=v.w;
    }
    __syncthreads();
    #pragma unroll
    for (int kk=0;kk<16;kk++){
      const float4 a4 = *reinterpret_cast<const float4*>(&As[kk][ty<<2]);
      const float4 b4 = *reinterpret_cast<const float4*>(&Bs[kk][tx<<2]);
      const float av[4]={a4.x,a4.y,a4.z,a4.w};
      const float bv[4]={b4.x,b4.y,b4.z,b4.w};
      #pragma unroll
      for (int i=0;i<4;i++)
        #pragma unroll
        for (int j=0;j<4;j++)
          acc[i][j]=fmaf(av[i],bv[j],acc[i][j]);
    }
    __syncthreads();
  }
  #pragma unroll
  for (int i=0;i<4;i++){
    const int r = row0 + (ty<<2) + i;
    if (r >= M) break;
    #pragma unroll
    for (int j=0;j<4;j++){
      const int c = col0 + (tx<<2) + j;
      if (c >= N) break;
      float v = acc[i][j];
      if (bias) v += bias[c];
      const size_t idx = (size_t)r*N + c;
      if (EPI==EPI_NONE)        C[idx]=v;
      else if (EPI==EPI_SILU)   C[idx]=v*sigf(v);
    }
  }
}

#define GEMM(EPI,TB,A,B,C,bias,M,N,K) \
  gemm_k<EPI,TB><<<dim3(((N)+63)/64,((M)+63)/64),dim3(256),0,stream>>>((A),(B),(C),(bias),(M),(N),(K))

// ---------------- bf16 MFMA GEMM: 128x128 tile, BK=64 ----------------------
enum { BEPI_F32=0, BEPI_BIAS_F32, BEPI_SILU_F32, BEPI_SIG_F32, BEPI_RELU2_BF16,
       BEPI_RES_GM, BEPI_RES_GP16, BEPI_TANH_BF16, BEPI_WDEC_F32 };

template<int EPI>
__global__ __launch_bounds__(256) void bgemm_k(
    const unsigned short* __restrict__ A, const unsigned short* __restrict__ B,
    void* __restrict__ Cv, const float* __restrict__ bias,
    const float* __restrict__ p1, const void* __restrict__ p2, int pstride,
    int M, int N, int K)
{
  __shared__ __align__(16) unsigned short As[128][64];
  __shared__ __align__(16) unsigned short Bs[128][64];
  const int tid = threadIdx.x;
  const int w = tid >> 6, lane = tid & 63;
  const int row0 = blockIdx.y * 128, col0 = blockIdx.x * 128;
  const int wr = w >> 1, wc = w & 1;
  const int l15 = lane & 15, l4 = lane >> 4;
  const int kkc = ((lane & 7) ^ (lane >> 3)) * 8;
  f32x4 acc[4][4] = {};
  for (int k0 = 0; k0 < K; k0 += 64) {
    #pragma unroll
    for (int i = 0; i < 4; i++) {
      const int rb = i*32 + w*8;
      const int r  = rb + (lane >> 3);
      GLDS16(A + (size_t)(row0 + r)*K + k0 + kkc, &As[rb][0]);
      GLDS16(B + (size_t)(col0 + r)*K + k0 + kkc, &Bs[rb][0]);
    }
    __syncthreads();
    #pragma unroll
    for (int ks = 0; ks < 2; ks++) {
      s16x8 af[4], bf[4];
      #pragma unroll
      for (int m = 0; m < 4; m++) {
        const int r = wr*64 + m*16 + l15;
        const int sl = (ks*4 + l4) ^ (r & 7);
        af[m] = *reinterpret_cast<const s16x8*>(&As[r][sl*8]);
      }
      #pragma unroll
      for (int n = 0; n < 4; n++) {
        const int r = wc*64 + n*16 + l15;
        const int sl = (ks*4 + l4) ^ (r & 7);
        bf[n] = *reinterpret_cast<const s16x8*>(&Bs[r][sl*8]);
      }
      #pragma unroll
      for (int m = 0; m < 4; m++)
        #pragma unroll
        for (int n = 0; n < 4; n++)
          acc[m][n] = __builtin_amdgcn_mfma_f32_16x16x32_bf16(af[m], bf[n], acc[m][n], 0, 0, 0);
    }
    __syncthreads();
  }
  float* Cf = (float*)Cv; unsigned short* Ch = (unsigned short*)Cv;
  const unsigned short* p2h = (const unsigned short*)p2;
  #pragma unroll
  for (int m = 0; m < 4; m++) {
    const int rbase = row0 + wr*64 + m*16 + (l4<<2);
    #pragma unroll
    for (int n = 0; n < 4; n++) {
      const int c = col0 + wc*64 + n*16 + l15;
      if (c >= N) continue;
      #pragma unroll
      for (int q = 0; q < 4; q++) {
        const int r = rbase + q;
        const int bb = r >> 8;
        float v = acc[m][n][q];
        const size_t idx = (size_t)r*N + c;
        if (EPI==BEPI_F32)            Cf[idx] = v;
        else if (EPI==BEPI_BIAS_F32)  Cf[idx] = v + bias[c];
        else if (EPI==BEPI_SILU_F32)  Cf[idx] = v*sigf(v);
        else if (EPI==BEPI_SIG_F32)   Cf[idx] = sigf(v);
        else if (EPI==BEPI_RELU2_BF16){ float t=fmaxf(v,0.f); Ch[idx] = f2b(t*t); }
        else if (EPI==BEPI_RES_GM)    Cf[idx] += p1[(size_t)bb*pstride + c]*v;
        else if (EPI==BEPI_RES_GP16)  Cf[idx] += p1[(size_t)bb*pstride + c]*(b2f(p2h[idx])*v);
        else if (EPI==BEPI_TANH_BF16) Ch[idx] = f2b(tanhf(v));
        else if (EPI==BEPI_WDEC_F32)  Cf[idx] = expf(-expf(v + p1[c]));
      }
    }
  }
}

#define BGEMM(EPI,A16,B16,Cp,bias,p1,p2,ps,M,N,K) \
  bgemm_k<EPI><<<dim3(((N)+127)/128,(M)/128),dim3(256),0,stream>>>( \
    (const unsigned short*)(A16),(const unsigned short*)(B16),(void*)(Cp),(bias),(p1),(p2),(ps),(M),(N),(K))

// ---------------- grouped bf16 GEMM (z = group id) ----------------
// epi: 0 f32, 1 silu f32, 3 relu2 bf16, 4 bf16, 5 silu bf16, 7 sig bf16
struct BGrp { const unsigned short* A; const unsigned short* B; void* C;
              int epi; int N; int gx; };
struct BGrp4 { BGrp g[4]; };

__global__ __launch_bounds__(256) void bgemm_grp_k(BGrp4 G, int M, int K)
{
  const BGrp gr = G.g[blockIdx.z];
  if ((int)blockIdx.x >= gr.gx) return;
  __shared__ __align__(16) unsigned short As[128][64];
  __shared__ __align__(16) unsigned short Bs[128][64];
  const int tid = threadIdx.x;
  const int w = tid >> 6, lane = tid & 63;
  const int row0 = blockIdx.y * 128, col0 = blockIdx.x * 128;
  const int wr = w >> 1, wc = w & 1;
  const int l15 = lane & 15, l4 = lane >> 4;
  const int kkc = ((lane & 7) ^ (lane >> 3)) * 8;
  const int N = gr.N;
  f32x4 acc[4][4] = {};
  for (int k0 = 0; k0 < K; k0 += 64) {
    #pragma unroll
    for (int i = 0; i < 4; i++) {
      const int rb = i*32 + w*8;
      const int r  = rb + (lane >> 3);
      GLDS16(gr.A + (size_t)(row0 + r)*K + k0 + kkc, &As[rb][0]);
      GLDS16(gr.B + (size_t)(col0 + r)*K + k0 + kkc, &Bs[rb][0]);
    }
    __syncthreads();
    #pragma unroll
    for (int ks = 0; ks < 2; ks++) {
      s16x8 af[4], bf[4];
      #pragma unroll
      for (int m = 0; m < 4; m++) {
        const int r = wr*64 + m*16 + l15;
        const int sl = (ks*4 + l4) ^ (r & 7);
        af[m] = *reinterpret_cast<const s16x8*>(&As[r][sl*8]);
      }
      #pragma unroll
      for (int n = 0; n < 4; n++) {
        const int r = wc*64 + n*16 + l15;
        const int sl = (ks*4 + l4) ^ (r & 7);
        bf[n] = *reinterpret_cast<const s16x8*>(&Bs[r][sl*8]);
      }
      #pragma unroll
      for (int m = 0; m < 4; m++)
        #pragma unroll
        for (int n = 0; n < 4; n++)
          acc[m][n] = __builtin_amdgcn_mfma_f32_16x16x32_bf16(af[m], bf[n], acc[m][n], 0, 0, 0);
    }
    __syncthreads();
  }
  float* Cf = (float*)gr.C; unsigned short* Ch = (unsigned short*)gr.C;
  #pragma unroll
  for (int m = 0; m < 4; m++) {
    const int rbase = row0 + wr*64 + m*16 + (l4<<2);
    #pragma unroll
    for (int n = 0; n < 4; n++) {
      const int c = col0 + wc*64 + n*16 + l15;
      #pragma unroll
      for (int q = 0; q < 4; q++) {
        const int r = rbase + q;
        float v = acc[m][n][q];
        const size_t idx = (size_t)r*N + c;
        switch (gr.epi) {
          case 0: Cf[idx] = v; break;
          case 1: Cf[idx] = v*sigf(v); break;
          case 3: { float t=fmaxf(v,0.f); Ch[idx] = f2b(t*t); } break;
          case 4: Ch[idx] = f2b(v); break;
          case 5: Ch[idx] = f2b(v*sigf(v)); break;
          default: Ch[idx] = f2b(sigf(v)); break;
        }
      }
    }
  }
}

// ---------------- conv stem ----------------
__global__ __launch_bounds__(256) void conv1_k(
    const float* __restrict__ x, const float* __restrict__ w,
    const float* __restrict__ bias, float* __restrict__ out)
{
  const int blk = blockIdx.x; const int bb = blk / 384; const int oc = blk % 384;
  __shared__ __align__(16) float sIn[4*1296];
  __shared__ __align__(16) float sW[100];
  const int tid = threadIdx.x;
  for (int idx=tid; idx<4*1296; idx+=256){
    int ic = idx/1296; int rem = idx - ic*1296;
    int yy = rem/36, xx = rem - yy*36;
    int gy = yy-2, gx = xx-2;
    float v = 0.f;
    if ((unsigned)gy < 32u && (unsigned)gx < 32u)
      v = x[(((size_t)bb*4+ic)*32+gy)*32+gx];
    sIn[idx]=v;
  }
  if (tid < 100) sW[tid] = w[(size_t)oc*100 + tid];
  __syncthreads();
  const float bv = bias[oc];
  #pragma unroll
  for (int i=0;i<4;i++){
    int p = tid + 256*i; int py=p>>5, px=p&31;
    int pb = py*36+px;
    float acc = bv;
    #pragma unroll
    for (int ic=0;ic<4;ic++)
      #pragma unroll
      for (int ky=0;ky<5;ky++)
        #pragma unroll
        for (int kx=0;kx<5;kx++)
          acc = fmaf(sIn[ic*1296 + pb + ky*36+kx], sW[ic*25+ky*5+kx], acc);
    out[((size_t)(bb*384+oc))*1024 + p] = acc*sigf(acc);
  }
}

__global__ __launch_bounds__(256) void gn_stats_nchw_k(
    const float* __restrict__ h, float* __restrict__ stats)
{
  const int blk = blockIdx.x;
  const size_t base = (size_t)blk*12288;
  const int tid = threadIdx.x;
  float s=0.f, s2=0.f;
  for (int idx=tid; idx<12288; idx+=256){ float v=h[base+idx]; s+=v; s2=fmaf(v,v,s2); }
  #pragma unroll
  for (int mask=32; mask>=1; mask>>=1){ s += __shfl_xor(s,mask); s2 += __shfl_xor(s2,mask); }
  __shared__ float ps[8];
  if ((tid&63)==0){ ps[tid>>6]=s; ps[4+(tid>>6)]=s2; }
  __syncthreads();
  if (tid==0){
    s = ps[0]+ps[1]+ps[2]+ps[3]; s2 = ps[4]+ps[5]+ps[6]+ps[7];
    float mean = s*(1.f/12288.f);
    float var  = s2*(1.f/12288.f) - mean*mean;
    stats[blk*2] = mean; stats[blk*2+1] = rsqrtf(var + 1e-5f);
  }
}

__global__ void zero16_k(unsigned short* __restrict__ p)
{
  size_t i = ((size_t)blockIdx.x*256 + threadIdx.x)*8;
  *reinterpret_cast<uint4*>(p + i) = make_uint4(0u,0u,0u,0u);
}

__global__ __launch_bounds__(256) void pad_apply_k(
    const float* __restrict__ img1, const float* __restrict__ stats,
    const float* __restrict__ w, const float* __restrict__ bgn,
    unsigned short* __restrict__ pad)
{
  __shared__ float t[8][33];
  const int b = blockIdx.x >> 5, y = blockIdx.x & 31;
  const int tid = threadIdx.x;
  for (int ic0 = 0; ic0 < 384; ic0 += 8) {
    const int icr = tid >> 5, xr = tid & 31;
    t[icr][xr] = img1[(((size_t)b*384 + ic0+icr)*32 + y)*32 + xr];
    __syncthreads();
    const int xw_ = tid >> 3, icw = tid & 7;
    const int ch = ic0 + icw;
    const int g = ch / 12;
    const float mean = stats[(b*32+g)*2], rstd = stats[(b*32+g)*2+1];
    float v = (t[icw][xw_] - mean)*rstd*w[ch] + bgn[ch];
    pad[(((size_t)b*36 + y+2)*36 + (xw_+2))*384 + ch] = f2b(v);
    __syncthreads();
  }
}

__global__ __launch_bounds__(256) void wrepack_k(
    const float* __restrict__ w, unsigned short* __restrict__ wtap)
{
  __shared__ float t[9600];
  const int oc = blockIdx.x; const int tid = threadIdx.x;
  for (int i=tid;i<9600;i+=256) t[i] = w[(size_t)oc*9600 + i];
  __syncthreads();
  for (int i=tid;i<9600;i+=256){
    int tap=i/384, ic=i-tap*384;
    wtap[((size_t)tap*384 + oc)*384 + ic] = f2b(t[ic*25+tap]);
  }
}

// conv2 implicit-GEMM, ic-outer / tap-inner, bf16 out, XCD-chunk swizzle
__global__ __launch_bounds__(256) void conv2m_k(
    const unsigned short* __restrict__ inp,
    const unsigned short* __restrict__ wtap,
    const float* __restrict__ bias, unsigned short* __restrict__ out)
{
  __shared__ __align__(16) unsigned short As[128][64];
  __shared__ __align__(16) unsigned short Bs[128][64];
  const int s = (blockIdx.x % 8) * 96 + blockIdx.x / 8;
  const int ot = s / 256; const int rem = s % 256;
  const int b = rem >> 3, pt = rem & 7;
  const int y0 = pt * 4, oc0 = ot * 128;
  const int tid = threadIdx.x, w = tid>>6, lane = tid&63;
  const int wr = w>>1, wc = w&1;
  const int l15 = lane & 15, l4 = lane >> 4;
  const int kkc = ((lane&7) ^ (lane>>3)) * 8;
  f32x4 acc[4][4] = {};
  for (int ic0 = 0; ic0 < 384; ic0 += 64) {
    for (int dy = 0; dy < 5; dy++) {
      for (int dx = 0; dx < 5; dx++) {
        const int tap = dy*5 + dx;
        #pragma unroll
        for (int i = 0; i < 4; i++) {
          const int rb = i*32 + w*8;
          const int r = rb + (lane>>3);
          const int py = r >> 5, px = r & 31;
          GLDS16(inp + (((size_t)(b*36 + y0+py+dy))*36 + (px+dx))*384 + ic0 + kkc, &As[rb][0]);
          GLDS16(wtap + ((size_t)tap*384 + oc0 + r)*384 + ic0 + kkc, &Bs[rb][0]);
        }
        __syncthreads();
        #pragma unroll
        for (int ks = 0; ks < 2; ks++) {
          s16x8 af[4], bf[4];
          #pragma unroll
          for (int m = 0; m < 4; m++) {
            const int r = wr*64 + m*16 + l15;
            const int sl = (ks*4 + l4) ^ (r & 7);
            af[m] = *reinterpret_cast<const s16x8*>(&As[r][sl*8]);
          }
          #pragma unroll
          for (int n = 0; n < 4; n++) {
            const int r = wc*64 + n*16 + l15;
            const int sl = (ks*4 + l4) ^ (r & 7);
            bf[n] = *reinterpret_cast<const s16x8*>(&Bs[r][sl*8]);
          }
          #pragma unroll
          for (int m = 0; m < 4; m++)
            #pragma unroll
            for (int n = 0; n < 4; n++)
              acc[m][n] = __builtin_amdgcn_mfma_f32_16x16x32_bf16(af[m], bf[n], acc[m][n], 0, 0, 0);
        }
        __syncthreads();
      }
    }
  }
  #pragma unroll
  for (int m = 0; m < 4; m++) {
    #pragma unroll
    for (int n = 0; n < 4; n++) {
      const int oc = oc0 + wc*64 + n*16 + l15;
      const float bv = bias[oc];
      #pragma unroll
      for (int q = 0; q < 4; q++) {
        const int p = wr*64 + m*16 + (l4<<2) + q;
        const int py = p >> 5, px = p & 31;
        float v = acc[m][n][q] + bv;
        out[((size_t)b*1024 + (y0+py)*32 + px)*384 + oc] = f2b(v*sigf(v));
      }
    }
  }
}

__global__ __launch_bounds__(256) void gn_stats_nhwc_k(
    const unsigned short* __restrict__ h, float* __restrict__ stats)
{
  const int b = blockIdx.x >> 5, g = blockIdx.x & 31;
  const int tid = threadIdx.x;
  float s=0.f, s2=0.f;
  for (int idx=tid; idx<12288; idx+=256){
    int p = idx/12, c = idx - p*12;
    float v = b2f(h[((size_t)b*1024+p)*384 + g*12 + c]);
    s+=v; s2=fmaf(v,v,s2);
  }
  #pragma unroll
  for (int mask=32; mask>=1; mask>>=1){ s += __shfl_xor(s,mask); s2 += __shfl_xor(s2,mask); }
  __shared__ float ps[8];
  if ((tid&63)==0){ ps[tid>>6]=s; ps[4+(tid>>6)]=s2; }
  __syncthreads();
  if (tid==0){
    s = ps[0]+ps[1]+ps[2]+ps[3]; s2 = ps[4]+ps[5]+ps[6]+ps[7];
    float mean = s*(1.f/12288.f);
    float var  = s2*(1.f/12288.f) - mean*mean;
    stats[(b*32+g)*2] = mean; stats[(b*32+g)*2+1] = rsqrtf(var + 1e-5f);
  }
}

__global__ void patchify_gn_k(const unsigned short* __restrict__ h, const float* __restrict__ stats,
                              const float* __restrict__ w, const float* __restrict__ bgn,
                              unsigned short* __restrict__ pm)
{
  int idx = blockIdx.x*256 + threadIdx.x;
  int row = idx/1536, f = idx - row*1536;
  int c = f>>2; int p=(f>>1)&1; int q=f&1;
  int bb=row>>8; int tok=row&255; int gh=tok>>4, gw=tok&15;
  int pix = (gh*2+p)*32 + gw*2+q;
  int g = c / 12;
  float mean = stats[(bb*32+g)*2], rstd = stats[(bb*32+g)*2+1];
  float v = (b2f(h[((size_t)bb*1024 + pix)*384 + c]) - mean)*rstd*w[c] + bgn[c];
  pm[idx] = f2b(v);
}

// ---------------- conditioning / misc ----------------
__global__ void temb_in_k(const float* __restrict__ t, float* __restrict__ out)
{
  int bb = blockIdx.x; int i = threadIdx.x;
  float fr = expf(-logf(10000.f) * (float)i / 128.f);
  float ang = t[bb]*fr;
  out[bb*256+i]     = cosf(ang);
  out[bb*256+128+i] = sinf(ang);
}

__global__ void siluc_k(const float* __restrict__ t2, const float* __restrict__ ytab,
                        const int* __restrict__ y, float* __restrict__ sc)
{
  int bb = blockIdx.x; int tid = threadIdx.x;
  int cls = y[bb];
  for (int c=tid; c<768; c+=256){
    float v = t2[bb*768+c] + ytab[(size_t)cls*768+c];
    sc[bb*768+c] = v*sigf(v);
  }
}

__global__ __launch_bounds__(256) void ln_mod_k(
    const float* __restrict__ in, float* __restrict__ out,
    const float* __restrict__ w, const float* __restrict__ b,
    const float* __restrict__ mod, int mstride, int sh_off, int sc_off, float eps)
{
  const int m = blockIdx.x; const int tid = threadIdx.x;
  const size_t base = (size_t)m*768;
  float v0=in[base+tid], v1=in[base+tid+256], v2=in[base+tid+512];
  float s = v0+v1+v2;
  float s2 = fmaf(v0,v0,fmaf(v1,v1,v2*v2));
  #pragma unroll
  for (int mask=32; mask>=1; mask>>=1){ s += __shfl_xor(s,mask); s2 += __shfl_xor(s2,mask); }
  __shared__ float ps[8];
  if ((tid&63)==0){ ps[tid>>6]=s; ps[4+(tid>>6)]=s2; }
  __syncthreads();
  s = ps[0]+ps[1]+ps[2]+ps[3]; s2 = ps[4]+ps[5]+ps[6]+ps[7];
  const float mean = s*(1.f/768.f);
  const float var  = s2*(1.f/768.f) - mean*mean;
  const float rstd = rsqrtf(var + eps);
  const int bb = m >> 8;
  #pragma unroll
  for (int k=0;k<3;k++){
    const int c = tid + k*256;
    float v = (k==0)?v0:((k==1)?v1:v2);
    float xh = (v-mean)*rstd;
    if (w) xh = fmaf(xh, w[c], b[c]);
    if (mod){
      float scv = mod[(size_t)bb*mstride + sc_off + c];
      float shv = mod[(size_t)bb*mstride + sh_off + c];
      xh = fmaf(xh, 1.f+scv, shv);
    }
    out[base+c] = xh;
  }
}

// fused LN+mod+token-shift (timemix); hmod/xx bf16
__global__ __launch_bounds__(256) void ln_shift_tm_k(
    const float* __restrict__ xs, const float* __restrict__ w, const float* __restrict__ b,
    const float* __restrict__ mod, const float* __restrict__ maa0,
    unsigned short* __restrict__ hmod16, unsigned short* __restrict__ xx16,
    unsigned short* __restrict__ xxx16)
{
  const int m = blockIdx.x, tid = threadIdx.x;
  const size_t base = (size_t)m*768;
  const int t = m & 255, bb = m >> 8;
  float c0=xs[base+tid], c1=xs[base+tid+256], c2=xs[base+tid+512];
  float p0=0.f,p1=0.f,p2=0.f;
  if (t) { p0=xs[base-768+tid]; p1=xs[base-512+tid]; p2=xs[base-256+tid]; }
  float sc_=c0+c1+c2, sc2=fmaf(c0,c0,fmaf(c1,c1,c2*c2));
  float sp_=p0+p1+p2, sp2=fmaf(p0,p0,fmaf(p1,p1,p2*p2));
  #pragma unroll
  for (int mask=32; mask>=1; mask>>=1){
    sc_+=__shfl_xor(sc_,mask); sc2+=__shfl_xor(sc2,mask);
    sp_+=__shfl_xor(sp_,mask); sp2+=__shfl_xor(sp2,mask);
  }
  __shared__ float ps[16];
  if ((tid&63)==0){ int wv=tid>>6; ps[wv]=sc_; ps[4+wv]=sc2; ps[8+wv]=sp_; ps[12+wv]=sp2; }
  __syncthreads();
  sc_=ps[0]+ps[1]+ps[2]+ps[3]; sc2=ps[4]+ps[5]+ps[6]+ps[7];
  sp_=ps[8]+ps[9]+ps[10]+ps[11]; sp2=ps[12]+ps[13]+ps[14]+ps[15];
  const float mc = sc_*(1.f/768.f), rc = rsqrtf(sc2*(1.f/768.f)-mc*mc + 1e-5f);
  const float mp = sp_*(1.f/768.f), rp = rsqrtf(sp2*(1.f/768.f)-mp*mp + 1e-5f);
  #pragma unroll
  for (int k=0;k<3;k++){
    const int c = tid + k*256;
    const float scv = mod[(size_t)bb*55296 + 768 + c];
    const float shv = mod[(size_t)bb*55296 + c];
    float cv = (k==0)?c0:((k==1)?c1:c2);
    float h = fmaf((cv-mc)*rc, w[c], b[c]);
    h = fmaf(h, 1.f+scv, shv);
    float pv = 0.f;
    if (t) {
      float pk = (k==0)?p0:((k==1)?p1:p2);
      pv = fmaf((pk-mp)*rp, w[c], b[c]);
      pv = fmaf(pv, 1.f+scv, shv);
    }
    const float d = pv - h;
    hmod16[base+c] = f2b(h);
    xx16[base+c] = f2b(d);
    xxx16[base+c] = f2b(fmaf(d, maa0[c], h));
  }
}

// fused LN+mod+token-shift (chanmix)
__global__ __launch_bounds__(256) void ln_shift_cm_k(
    const float* __restrict__ xs, const float* __restrict__ w, const float* __restrict__ b,
    const float* __restrict__ mod, const float* __restrict__ fmaa,
    unsigned short* __restrict__ xk16, unsigned short* __restrict__ xr16)
{
  const int m = blockIdx.x, tid = threadIdx.x;
  const size_t base = (size_t)m*768;
  const int t = m & 255, bb = m >> 8;
  float c0=xs[base+tid], c1=xs[base+tid+256], c2=xs[base+tid+512];
  float p0=0.f,p1=0.f,p2=0.f;
  if (t) { p0=xs[base-768+tid]; p1=xs[base-512+tid]; p2=xs[base-256+tid]; }
  float sc_=c0+c1+c2, sc2=fmaf(c0,c0,fmaf(c1,c1,c2*c2));
  float sp_=p0+p1+p2, sp2=fmaf(p0,p0,fmaf(p1,p1,p2*p2));
  #pragma unroll
  for (int mask=32; mask>=1; mask>>=1){
    sc_+=__shfl_xor(sc_,mask); sc2+=__shfl_xor(sc2,mask);
    sp_+=__shfl_xor(sp_,mask); sp2+=__shfl_xor(sp2,mask);
  }
  __shared__ float ps[16];
  if ((tid&63)==0){ int wv=tid>>6; ps[wv]=sc_; ps[4+wv]=sc2; ps[8+wv]=sp_; ps[12+wv]=sp2; }
  __syncthreads();
  sc_=ps[0]+ps[1]+ps[2]+ps[3]; sc2=ps[4]+ps[5]+ps[6]+ps[7];
  sp_=ps[8]+ps[9]+ps[10]+ps[11]; sp2=ps[12]+ps[13]+ps[14]+ps[15];
  const float mc = sc_*(1.f/768.f), rc = rsqrtf(sc2*(1.f/768.f)-mc*mc + 1e-5f);
  const float mp = sp_*(1.f/768.f), rp = rsqrtf(sp2*(1.f/768.f)-mp*mp + 1e-5f);
  #pragma unroll
  for (int k=0;k<3;k++){
    const int c = tid + k*256;
    const float scv = mod[(size_t)bb*55296 + 3072 + c];
    const float shv = mod[(size_t)bb*55296 + 2304 + c];
    float cv = (k==0)?c0:((k==1)?c1:c2);
    float h = fmaf((cv-mc)*rc, w[c], b[c]);
    h = fmaf(h, 1.f+scv, shv);
    float pv = 0.f;
    if (t) {
      float pk = (k==0)?p0:((k==1)?p1:p2);
      pv = fmaf((pk-mp)*rp, w[c], b[c]);
      pv = fmaf(pv, 1.f+scv, shv);
    }
    const float d = pv - h;
    xk16[base+c] = f2b(fmaf(d, fmaa[c], h));
    xr16[base+c] = f2b(fmaf(d, fmaa[768+c], h));
  }
}

// 16 rows/block (512 blocks); tm_w2 fp32 (bf16 variant regressed: VALU-bound)
__global__ __launch_bounds__(256) void five_mix_k(
    const unsigned short* __restrict__ mix16, const float* __restrict__ w2,
    const unsigned short* __restrict__ hmod16, const unsigned short* __restrict__ xx16,
    const float* __restrict__ maa15,
    unsigned short* __restrict__ xw, unsigned short* __restrict__ xk,
    unsigned short* __restrict__ xv, unsigned short* __restrict__ xr,
    unsigned short* __restrict__ xg)
{
  __shared__ __align__(16) float smix[16][160];
  const int m0 = blockIdx.x * 16;
  const int tid = threadIdx.x;
  for (int idx=tid; idx<16*160; idx+=256){
    int r = idx/160, d = idx - r*160;
    smix[r][d] = b2f(mix16[(size_t)(m0+r)*160 + d]);
  }
  __syncthreads();
  #pragma unroll 1
  for (int cc=0; cc<3; cc++){
    const int c = tid + cc*256;
    float hv[16], xv_[16];
    #pragma unroll
    for (int r=0;r<16;r++){
      size_t id=(size_t)(m0+r)*768+c;
      hv[r]=b2f(hmod16[id]); xv_[r]=b2f(xx16[id]);
    }
    #pragma unroll 1
    for (int f=0; f<5; f++){
      float acc[16];
      const float base = maa15[f*768 + c];
      #pragma unroll
      for (int r=0;r<16;r++) acc[r]=base;
      #pragma unroll 1
      for (int d4=0; d4<8; d4++){
        float wv[4];
        #pragma unroll
        for (int q=0;q<4;q++) wv[q] = w2[(size_t)(f*32+d4*4+q)*768 + c];
        #pragma unroll
        for (int r=0;r<16;r++){
          const float4 mv = *reinterpret_cast<const float4*>(&smix[r][f*32+d4*4]);
          acc[r] = fmaf(mv.x,wv[0],fmaf(mv.y,wv[1],fmaf(mv.z,wv[2],fmaf(mv.w,wv[3],acc[r]))));
        }
      }
      #pragma unroll
      for (int r=0;r<16;r++){
        float val = fmaf(xv_[r], acc[r], hv[r]);
        size_t id = (size_t)(m0+r)*768+c;
        if (f==0) xw[id]=f2b(val);
        else if (f==1) xk[id]=f2b(val);
        else if (f==2) xv[id]=f2b(val);
        else if (f==3) xr[id]=f2b(val);
        else           xg[id]=f2b(val);
      }
    }
  }
}

// ---------------- chunked MFMA WKV (fused head-GN + gate) -------------------
__global__ __launch_bounds__(256) void wkv_k(
    const unsigned short* __restrict__ rg, const unsigned short* __restrict__ kg,
    const unsigned short* __restrict__ vg, const float* __restrict__ wg,
    const unsigned short* __restrict__ gg, const float* __restrict__ u,
    const float* __restrict__ lnxw, const float* __restrict__ lnxb,
    unsigned short* __restrict__ out16)
{
  const int bh = blockIdx.x; const int b = bh/12, h = bh%12;
  const int tid = threadIdx.x;
  const int w = tid >> 6, lane = tid & 63;
  const int l4 = lane >> 4, l15 = lane & 15;
  __shared__ __align__(16) unsigned short r16s[32][64], k16s[32][64], v16s[32][64], g16s[32][64];
  __shared__ __align__(16) float wds[32][64];
  __shared__ __align__(16) float Wl[33][64];
  __shared__ __align__(16) unsigned short rr16[32][64], kk16[32][64];
  __shared__ __align__(16) unsigned short kk2T[64][32], vT[64][32];
  __shared__ __align__(16) unsigned short S16T[64][64];
  __shared__ __align__(16) unsigned short A16[32][32];
  __shared__ float diag[32], ypsum[32][4], ypsq[32][4];

  reinterpret_cast<uint4*>(&S16T[0][0])[tid] = make_uint4(0,0,0,0);
  reinterpret_cast<uint4*>(&S16T[0][0])[256+tid] = make_uint4(0,0,0,0);

  const float u_lane = u[h*64 + lane];
  const int jj = w*16 + l15;
  const float lw = lnxw[h*64 + jj], lb = lnxb[h*64 + jj];
  const size_t gb = (size_t)(b*256)*768 + h*64;

  const int st_t = tid >> 3, st_i = (tid & 7) * 8;
  uint4 pr, pk, pv, pg; float4 pw0, pw1;

#define WKV_LOADC(c_) { \
    const size_t tb = gb + (size_t)((c_)*32 + st_t)*768 + st_i; \
    pr = *reinterpret_cast<const uint4*>(rg + tb); \
    pk = *reinterpret_cast<const uint4*>(kg + tb); \
    pv = *reinterpret_cast<const uint4*>(vg + tb); \
    pg = *reinterpret_cast<const uint4*>(gg + tb); \
    pw0 = *reinterpret_cast<const float4*>(wg + tb); \
    pw1 = *reinterpret_cast<const float4*>(wg + tb + 4); }
#define WKV_STAGE() { \
    *reinterpret_cast<uint4*>(&r16s[st_t][st_i]) = pr; \
    *reinterpret_cast<uint4*>(&k16s[st_t][st_i]) = pk; \
    *reinterpret_cast<uint4*>(&v16s[st_t][st_i]) = pv; \
    *reinterpret_cast<uint4*>(&g16s[st_t][st_i]) = pg; \
    *reinterpret_cast<float4*>(&wds[st_t][st_i]) = pw0; \
    *reinterpret_cast<float4*>(&wds[st_t][st_i+4]) = pw1; }

  f32x4 S_acc[4] = {};

  WKV_LOADC(0);
  WKV_STAGE();
  __syncthreads();

  #pragma unroll 1
  for (int c = 0; c < 8; ++c) {
    if (w == 0) {
      float wv[32];
      #pragma unroll
      for (int t=0;t<32;t++) wv[t] = wds[t][lane];
      float P = 1.f;
      Wl[0][lane] = 1.f;
      #pragma unroll
      for (int t=0;t<32;t++){ P *= wv[t]; Wl[t+1][lane] = P; }
    }
    __syncthreads();
    {
      const int t = st_t, i0 = st_i;
      s16x8 rv = *reinterpret_cast<const s16x8*>(&r16s[t][i0]);
      s16x8 kv = *reinterpret_cast<const s16x8*>(&k16s[t][i0]);
      s16x8 vv = *reinterpret_cast<const s16x8*>(&v16s[t][i0]);
      float4 wa0 = *reinterpret_cast<const float4*>(&Wl[t][i0]);
      float4 wa1 = *reinterpret_cast<const float4*>(&Wl[t][i0+4]);
      float4 wb0 = *reinterpret_cast<const float4*>(&Wl[t+1][i0]);
      float4 wb1 = *reinterpret_cast<const float4*>(&Wl[t+1][i0+4]);
      float4 wf0 = *reinterpret_cast<const float4*>(&Wl[32][i0]);
      float4 wf1 = *reinterpret_cast<const float4*>(&Wl[32][i0+4]);
      float wt_[8] = {wa0.x,wa0.y,wa0.z,wa0.w,wa1.x,wa1.y,wa1.z,wa1.w};
      float wt1[8] = {wb0.x,wb0.y,wb0.z,wb0.w,wb1.x,wb1.y,wb1.z,wb1.w};
      float w32[8] = {wf0.x,wf0.y,wf0.z,wf0.w,wf1.x,wf1.y,wf1.z,wf1.w};
      s16x8 rro, kko;
      #pragma unroll
      for (int e=0;e<8;e++){
        const int i = i0 + e;
        float rf = b2f((unsigned short)rv[e]) * wt_[e];
        float kf = b2f((unsigned short)kv[e]) / wt1[e];
        rro[e] = (short)f2b(rf);
        kko[e] = (short)f2b(kf);
        kk2T[i][(((t>>3)^(i&3))<<3) + (t&7)] = f2b(kf * w32[e]);
        vT[i][(((t>>3)^(i&3))<<3) + (t&7)] = (unsigned short)vv[e];
      }
      const int sc_ = ((i0>>3)^(t&7))<<3;
      *reinterpret_cast<s16x8*>(&rr16[t][sc_]) = rro;
      *reinterpret_cast<s16x8*>(&kk16[t][sc_]) = kko;
      #pragma unroll
      for (int tt=0;tt<8;tt++){
        const int td = w*8 + tt;
        float p = b2f(r16s[td][lane]) * u_lane * b2f(k16s[td][lane]);
        #pragma unroll
        for (int mask=32; mask>=1; mask>>=1) p += __shfl_xor(p, mask);
        if (lane==0) diag[td] = p;
      }
    }
    __syncthreads();
    if (c < 7) WKV_LOADC(c+1);
    f32x4 Y[2] = {};
    s16x8 rrf[2][2];
    #pragma unroll
    for (int m=0;m<2;m++)
      #pragma unroll
      for (int kt=0;kt<2;kt++){
        const int row = m*16 + l15;
        rrf[m][kt] = *reinterpret_cast<const s16x8*>(&rr16[row][(((kt*4+l4)^(row&7))<<3)]);
      }
    #pragma unroll
    for (int m=0;m<2;m++)
      #pragma unroll
      for (int kt=0;kt<2;kt++){
        s16x8 sf = *reinterpret_cast<const s16x8*>(&S16T[jj][(((kt*4+l4)^(jj&7))<<3)]);
        Y[m] = __builtin_amdgcn_mfma_f32_16x16x32_bf16(rrf[m][kt], sf, Y[m], 0,0,0);
      }
    s16x8 vtf = *reinterpret_cast<const s16x8*>(&vT[jj][((l4^(jj&3))<<3)]);
    #pragma unroll
    for (int m=0;m<4;m++){
      const int row = m*16 + l15;
      s16x8 k2f = *reinterpret_cast<const s16x8*>(&kk2T[row][((l4^(row&3))<<3)]);
      #pragma unroll
      for (int q=0;q<4;q++) S_acc[m][q] *= Wl[32][m*16 + l4*4 + q];
      S_acc[m] = __builtin_amdgcn_mfma_f32_16x16x32_bf16(k2f, vtf, S_acc[m], 0,0,0);
    }
    if (w == 0) {
      f32x4 Aac[2][2] = {};
      #pragma unroll
      for (int m=0;m<2;m++)
        #pragma unroll
        for (int n=0;n<2;n++)
          #pragma unroll
          for (int kt=0;kt<2;kt++){
            const int srow = n*16 + l15;
            s16x8 kf = *reinterpret_cast<const s16x8*>(&kk16[srow][(((kt*4+l4)^(srow&7))<<3)]);
            Aac[m][n] = __builtin_amdgcn_mfma_f32_16x16x32_bf16(rrf[m][kt], kf, Aac[m][n], 0,0,0);
          }
      #pragma unroll
      for (int m=0;m<2;m++)
        #pragma unroll
        for (int n=0;n<2;n++)
          #pragma unroll
          for (int q=0;q<4;q++){
            const int t = m*16 + l4*4 + q;
            const int s = n*16 + l15;
            float av = Aac[m][n][q];
            av = (s < t) ? av : ((s == t) ? diag[t] : 0.f);
            A16[t][(((s>>3)^(t&3))<<3) + (s&7)] = f2b(av);
          }
    }
    #pragma unroll
    for (int m=0;m<4;m++)
      #pragma unroll
      for (int q=0;q<4;q++){
        const int i = m*16 + l4*4 + q;
        S16T[jj][(((i>>3)^(jj&7))<<3) + (i&7)] = f2b(S_acc[m][q]);
      }
    __syncthreads();
    #pragma unroll
    for (int m=0;m<2;m++){
      const int row = m*16 + l15;
      s16x8 af = *reinterpret_cast<const s16x8*>(&A16[row][((l4^(row&3))<<3)]);
      Y[m] = __builtin_amdgcn_mfma_f32_16x16x32_bf16(af, vtf, Y[m], 0,0,0);
    }
    #pragma unroll
    for (int m=0;m<2;m++)
      #pragma unroll
      for (int q=0;q<4;q++){
        float s1 = Y[m][q], s2 = s1*s1;
        #pragma unroll
        for (int mask=8; mask>=1; mask>>=1){ s1 += __shfl_xor(s1,mask); s2 += __shfl_xor(s2,mask); }
        if (l15==0){ const int t = m*16 + l4*4 + q; ypsum[t][w]=s1; ypsq[t][w]=s2; }
      }
    __syncthreads();
    #pragma unroll
    for (int m=0;m<2;m++)
      #pragma unroll
      for (int q=0;q<4;q++){
        const int t = m*16 + l4*4 + q;
        float s1 = ypsum[t][0]+ypsum[t][1]+ypsum[t][2]+ypsum[t][3];
        float s2 = ypsq[t][0]+ypsq[t][1]+ypsq[t][2]+ypsq[t][3];
        float mean = s1*(1.f/64.f);
        float var  = s2*(1.f/64.f) - mean*mean;
        float xh = (Y[m][q]-mean)*rsqrtf(var + 6.4e-4f);
        float o = fmaf(xh, lw, lb) * b2f(g16s[t][jj]);
        out16[gb + (size_t)(c*32+t)*768 + jj] = f2b(o);
      }
    if (c < 7) {
      __syncthreads();
      WKV_STAGE();
      __syncthreads();
    }
  }
#undef WKV_LOADC
#undef WKV_STAGE
}

__global__ void unpatch_k(const float* __restrict__ po, float* __restrict__ out)
{
  int idx = blockIdx.x*256 + threadIdx.x;
  int xq=idx&31; int yy=(idx>>5)&31; int ch=(idx>>10)&3; int bb=idx>>12;
  int gh=yy>>1, p=yy&1, gw=xq>>1, q=xq&1;
  out[idx] = po[((size_t)(bb*256+gh*16+gw))*16 + p*8+q*4+ch];
}

// ---------------- fp32 -> bf16 conversions / repacks ----------------
__global__ void f2b_k(const float* __restrict__ s, unsigned short* __restrict__ d)
{
  size_t i = ((size_t)blockIdx.x*256 + threadIdx.x)*8;
  float4 a = *reinterpret_cast<const float4*>(s+i);
  float4 b = *reinterpret_cast<const float4*>(s+i+4);
  s16x8 o;
  o[0]=(short)f2b(a.x); o[1]=(short)f2b(a.y); o[2]=(short)f2b(a.z); o[3]=(short)f2b(a.w);
  o[4]=(short)f2b(b.x); o[5]=(short)f2b(b.y); o[6]=(short)f2b(b.z); o[7]=(short)f2b(b.w);
  *reinterpret_cast<s16x8*>(d + i) = o;
}

// merged per-layer weight convert + mix/decay repack.
// blocks [0,3744): bulk convert r,k,v,o,g,fr (589824 ea), fk, fv (2064384 ea)
// blocks [3744,5088): repack tm_w1->(256,768), td_w1->(128,768), td_w2->(768,64)
__global__ void f2bw_layer_k(
    const float* __restrict__ r_, const float* __restrict__ k_, const float* __restrict__ v_,
    const float* __restrict__ o_, const float* __restrict__ g_, const float* __restrict__ fr_,
    const float* __restrict__ fk_, const float* __restrict__ fv_,
    const float* __restrict__ tm1, const float* __restrict__ td1, const float* __restrict__ td2,
    unsigned short* __restrict__ dst)
{
  if (blockIdx.x < 3744) {
    size_t i = ((size_t)blockIdx.x*256 + threadIdx.x)*8;
    const float* s; size_t off;
    if (i < 3538944) {
      unsigned seg = (unsigned)(i / 589824u); off = i - (size_t)seg*589824u;
      s = seg==0?r_:seg==1?k_:seg==2?v_:seg==3?o_:seg==4?g_:fr_;
    } else if (i < 5603328) { s = fk_; off = i - 3538944; }
    else                    { s = fv_; off = i - 5603328; }
    float4 a = *reinterpret_cast<const float4*>(s+off);
    float4 b = *reinterpret_cast<const float4*>(s+off+4);
    s16x8 o;
    o[0]=(short)f2b(a.x); o[1]=(short)f2b(a.y); o[2]=(short)f2b(a.z); o[3]=(short)f2b(a.w);
    o[4]=(short)f2b(b.x); o[5]=(short)f2b(b.y); o[6]=(short)f2b(b.z); o[7]=(short)f2b(b.w);
    *reinterpret_cast<s16x8*>(dst + i) = o;
  } else {
    int idx = (blockIdx.x-3744)*256 + threadIdx.x;   // 0..344063
    unsigned short* rp = dst + 7667712;
    if (idx < 196608) {
      int n = idx/768, k = idx - n*768;
      rp[idx] = (n<160) ? f2b(tm1[(size_t)k*160 + n]) : (unsigned short)0;
    } else if (idx < 294912) {
      int i = idx-196608; int n = i/768, k = i - n*768;
      rp[idx] = (n<64) ? f2b(td1[(size_t)k*64 + n]) : (unsigned short)0;
    } else {
      int i = idx-294912; int n = i/64, k = i - n*64;
      rp[idx] = f2b(td2[(size_t)k*768 + n]);
    }
  }
}

// ---------------------------------------------------------------------------
extern "C" void kernel_launch(void* const* d_in, const int* in_sizes, int n_in,
                              void* d_out, int out_size, void* d_ws, size_t ws_size,
                              hipStream_t stream)
{
  const float* x_in  = (const float*)d_in[0];
  const float* t_in  = (const float*)d_in[1];
  const int*   y_in  = (const int*)  d_in[2];
  const float* c1w   = (const float*)d_in[3];
  const float* c1b   = (const float*)d_in[4];
  const float* gn1w  = (const float*)d_in[5];
  const float* gn1b  = (const float*)d_in[6];
  const float* c2w   = (const float*)d_in[7];
  const float* c2b   = (const float*)d_in[8];
  const float* gn2w  = (const float*)d_in[9];
  const float* gn2b  = (const float*)d_in[10];
  const float* xew   = (const float*)d_in[11];
  const float* xeb   = (const float*)d_in[12];
  const float* tew1  = (const float*)d_in[13];
  const float* teb1  = (const float*)d_in[14];
  const float* tew2  = (const float*)d_in[15];
  const float* teb2  = (const float*)d_in[16];
  const float* ytab  = (const float*)d_in[17];
  const float* ln0w  = (const float*)d_in[18];
  const float* ln0b  = (const float*)d_in[19];
  const float* ln1w  = (const float*)d_in[20];
  const float* ln1b  = (const float*)d_in[21];
  const float* ln2w  = (const float*)d_in[22];
  const float* ln2b  = (const float*)d_in[23];
  const float* amaa  = (const float*)d_in[24];
  const float* tmw1  = (const float*)d_in[25];
  const float* tmw2  = (const float*)d_in[26];
  const float* tdv   = (const float*)d_in[27];
  const float* tdw1  = (const float*)d_in[28];
  const float* tdw2  = (const float*)d_in[29];
  const float* faa   = (const float*)d_in[30];
  const float* rw    = (const float*)d_in[31];
  const float* kw    = (const float*)d_in[32];
  const float* vw    = (const float*)d_in[33];
  const float* ow    = (const float*)d_in[34];
  const float* gw    = (const float*)d_in[35];
  const float* lnxw  = (const float*)d_in[36];
  const float* lnxb  = (const float*)d_in[37];
  const float* fmaa  = (const float*)d_in[38];
  const float* fkw   = (const float*)d_in[39];
  const float* frw   = (const float*)d_in[40];
  const float* fvw   = (const float*)d_in[41];
  const float* adaw  = (const float*)d_in[42];
  const float* adab  = (const float*)d_in[43];
  const float* flaw  = (const float*)d_in[44];
  const float* flab  = (const float*)d_in[45];
  const float* flw   = (const float*)d_in[46];
  const float* flb   = (const float*)d_in[47];

  float* Wf = (float*)d_ws;
  float* xs   = Wf+O_XS;   float* hmodf = Wf+O_HMOD;
  float* ada  = Wf+O_ADA;  float* fla  = Wf+O_FLA;
  float* t2   = Wf+O_T2;   float* sc   = Wf+O_SC;
  float* ti   = Wf+O_TI;   float* t1   = Wf+O_T1;
  float* st1  = Wf+O_ST1;  float* st2  = Wf+O_ST2;
  unsigned short* xew16 = (unsigned short*)(Wf+O_XEW16);
  unsigned short* wl16  = (unsigned short*)(Wf+O_WL16);
  unsigned short* hmod16 = (unsigned short*)(Wf+O_HMOD);
  float* big = Wf+O_BIG;
  float* wd   = big+L_WD;
  unsigned short* xx16  = (unsigned short*)(big+L_XX);
  unsigned short* rb16  = (unsigned short*)(big+L_XXX);
  unsigned short* kb16  = (unsigned short*)(big+L_KB);
  unsigned short* vb16  = (unsigned short*)(big+L_VB);
  unsigned short* gb16  = (unsigned short*)(big+L_GB);
  unsigned short* xw16  = (unsigned short*)(big+L_XW);
  unsigned short* xxx16 = (unsigned short*)(big+L_XXX);
  unsigned short* mixb16= (unsigned short*)(big+L_MIXB);
  unsigned short* wt16  = (unsigned short*)(big+L_WT);
  unsigned short* xk16 = (unsigned short*)(big+L_XK16);
  unsigned short* xv16 = (unsigned short*)(big+L_XV16);
  unsigned short* xr16 = (unsigned short*)(big+L_XR16);
  unsigned short* xg16 = (unsigned short*)(big+L_XG16);
  unsigned short* gnh16 = (unsigned short*)(big+L_GNH16);
  unsigned short* kbig16 = (unsigned short*)(big+L_KBIG16);
  float* img1 = big+S_IMG1;
  unsigned short* img2_16 = (unsigned short*)(big+S_IMG2);
  unsigned short* pad16  = (unsigned short*)(big+S_PAD16);
  unsigned short* wtap16 = (unsigned short*)(big+S_WTAP16);
  unsigned short* pm16   = (unsigned short*)(big+S_PM16);
  float* pout = big+L_MIXB;
  unsigned short* dr  = wl16;
  unsigned short* dk  = wl16 + 589824;
  unsigned short* dv  = wl16 + 1179648;
  unsigned short* do_ = wl16 + 1769472;
  unsigned short* dg  = wl16 + 2359296;
  unsigned short* dfr = wl16 + 2949120;
  unsigned short* dfk = wl16 + 3538944;
  unsigned short* dfv = wl16 + 5603328;
  unsigned short* dtm1t = wl16 + 7667712;
  unsigned short* dtd1t = wl16 + 7864320;
  unsigned short* dtd2t = wl16 + 7962624;   // (768 x 64)

  // ---- conv stem ----
  conv1_k<<<dim3(32*384),dim3(256),0,stream>>>(x_in, c1w, c1b, img1);
  gn_stats_nchw_k<<<dim3(1024),dim3(256),0,stream>>>(img1, st1);
  zero16_k<<<dim3(7776),dim3(256),0,stream>>>(pad16);
  pad_apply_k<<<dim3(1024),dim3(256),0,stream>>>(img1, st1, gn1w, gn1b, pad16);
  wrepack_k<<<dim3(384),dim3(256),0,stream>>>(c2w, wtap16);
  conv2m_k<<<dim3(768),dim3(256),0,stream>>>(pad16, wtap16, c2b, img2_16);
  gn_stats_nhwc_k<<<dim3(1024),dim3(256),0,stream>>>(img2_16, st2);
  patchify_gn_k<<<dim3(49152),dim3(256),0,stream>>>(img2_16, st2, gn2w, gn2b, pm16);
  f2b_k<<<dim3(576),dim3(256),0,stream>>>(xew, xew16);
  BGEMM(BEPI_BIAS_F32, pm16, xew16, xs, xeb, nullptr,nullptr,0, 8192,768,1536);

  // ---- conditioning ----
  temb_in_k<<<dim3(32),dim3(128),0,stream>>>(t_in, ti);
  GEMM(EPI_SILU,true, ti, tew1, t1, teb1, 32,768,256);
  GEMM(EPI_NONE,true, t1, tew2, t2, teb2, 32,768,768);
  siluc_k<<<dim3(32),dim3(256),0,stream>>>(t2, ytab, y_in, sc);
  GEMM(EPI_NONE,true, sc, adaw, ada, adab, 32,55296,768);
  GEMM(EPI_NONE,true, sc, flaw, fla, flab, 32,1536,768);

  // ---- ln0 ----
  ln_mod_k<<<dim3(8192),dim3(256),0,stream>>>(xs, xs, ln0w, ln0b, nullptr, 0,0,0, 1e-5f);

  for (int l=0; l<12; l++){
    const float* adal = ada + (size_t)l*4608;
    f2bw_layer_k<<<dim3(5088),dim3(256),0,stream>>>(
        rw+(size_t)l*589824, kw+(size_t)l*589824, vw+(size_t)l*589824,
        ow+(size_t)l*589824, gw+(size_t)l*589824, frw+(size_t)l*589824,
        fkw+(size_t)l*2064384, fvw+(size_t)l*2064384,
        tmw1+(size_t)l*122880, tdw1+(size_t)l*49152, tdw2+(size_t)l*49152, wl16);
    // --- timemix ---
    ln_shift_tm_k<<<dim3(8192),dim3(256),0,stream>>>(
        xs, ln1w+(size_t)l*768, ln1b+(size_t)l*768, adal, amaa+(size_t)l*4608,
        hmod16, xx16, xxx16);
    BGEMM(BEPI_TANH_BF16, xxx16, dtm1t, mixb16, nullptr,nullptr,nullptr,0, 8192,160,768);
    five_mix_k<<<dim3(512),dim3(256),0,stream>>>(mixb16, tmw2+(size_t)l*122880, hmod16, xx16,
                                                 amaa+(size_t)l*4608+768, xw16,xk16,xv16,xr16,xg16);
    BGEMM(BEPI_TANH_BF16, xw16, dtd1t, wt16, nullptr,nullptr,nullptr,0, 8192,64,768);
    BGEMM(BEPI_WDEC_F32, wt16, dtd2t, wd, nullptr, tdv+(size_t)l*768, nullptr,0, 8192,768,64);
    {
      BGrp4 G;
      G.g[0].A=xr16; G.g[0].B=dr; G.g[0].C=rb16; G.g[0].epi=4; G.g[0].N=768; G.g[0].gx=6;
      G.g[1].A=xk16; G.g[1].B=dk; G.g[1].C=kb16; G.g[1].epi=4; G.g[1].N=768; G.g[1].gx=6;
      G.g[2].A=xv16; G.g[2].B=dv; G.g[2].C=vb16; G.g[2].epi=4; G.g[2].N=768; G.g[2].gx=6;
      G.g[3].A=xg16; G.g[3].B=dg; G.g[3].C=gb16; G.g[3].epi=5; G.g[3].N=768; G.g[3].gx=6;
      bgemm_grp_k<<<dim3(6,64,4),dim3(256),0,stream>>>(G, 8192, 768);
    }
    wkv_k<<<dim3(384),dim3(256),0,stream>>>(rb16, kb16, vb16, wd, gb16, faa+(size_t)l*768,
                                            lnxw+(size_t)l*768, lnxb+(size_t)l*768, gnh16);
    BGEMM(BEPI_RES_GM, gnh16, do_, xs, nullptr, adal+1536, nullptr, 55296, 8192,768,768);
    // --- chanmix ---
    ln_shift_cm_k<<<dim3(8192),dim3(256),0,stream>>>(
        xs, ln2w+(size_t)l*768, ln2b+(size_t)l*768, adal, fmaa+(size_t)l*1536, xk16, xr16);
    {
      BGrp4 G;
      G.g[0].A=xk16; G.g[0].B=dfk; G.g[0].C=kbig16; G.g[0].epi=3; G.g[0].N=2688; G.g[0].gx=21;
      G.g[1].A=xr16; G.g[1].B=dfr; G.g[1].C=gb16;   G.g[1].epi=7; G.g[1].N=768;  G.g[1].gx=6;
      G.g[2]=G.g[1]; G.g[3]=G.g[1];
      bgemm_grp_k<<<dim3(21,64,2),dim3(256),0,stream>>>(G, 8192, 768);
    }
    BGEMM(BEPI_RES_GP16, kbig16, dfv, xs, nullptr, adal+3840, gb16, 55296, 8192,768,2688);
  }

  // ---- final layer ----
  ln_mod_k<<<dim3(8192),dim3(256),0,stream>>>(xs, hmodf, nullptr, nullptr, fla, 1536, 0, 768, 1e-6f);
  GEMM(EPI_NONE,true, hmodf, flw, pout, flb, 8192,16,768);
  unpatch_k<<<dim3(512),dim3(256),0,stream>>>(pout, (float*)d_out);
}